// Round 11
// baseline (1253.508 us; speedup 1.0000x reference)
//
#include <hip/hip_runtime.h>
#include <hip/hip_bf16.h>
#include <stdint.h>

#define M_TIME 64
#define N_DICT 20000
#define B_VOX  8192

#define NTILES 313    // ceil(20000/64); last tile padded with zeros

typedef _Float16 v8h __attribute__((ext_vector_type(8)));   // 8 f16 (4 VGPRs)
typedef _Float16 v4h __attribute__((ext_vector_type(4)));   // 8 B store unit
typedef float    v4f __attribute__((ext_vector_type(4)));
typedef __attribute__((address_space(3))) unsigned int  lds_u32;
typedef const __attribute__((address_space(1))) unsigned int glb_u32;

__device__ __forceinline__ unsigned long long u64max(unsigned long long a, unsigned long long b) { return a > b ? a : b; }
__device__ __forceinline__ unsigned umin32(unsigned a, unsigned b) { return a < b ? a : b; }
__device__ __forceinline__ unsigned umax32(unsigned a, unsigned b) { return a > b ? a : b; }

// ---------------------------------------------------------------------------
// Prepass: convert y to f16 ONCE, packed in A-fragment order.
// Tile T = 16 fragment-rows fr = (arr*2 + h)*4 + quad; row = 64 n x 8 f16
// (k = h*32 + quad*8 + j). 16 KB/tile. f16 y + exact hi/lo input split gives
// sim rel-err ~6e-4, 30x inside the 2% exact-rescue margin.
// ---------------------------------------------------------------------------
__global__ __launch_bounds__(256) void split_y(
    const float* __restrict__ yr, const float* __restrict__ yi,
    v4h* __restrict__ yp)
{
    const int u = blockIdx.x * 256 + threadIdx.x;   // [arr][T][kq][n_l]
    const int n_l = u & 63;
    const int kq  = (u >> 6) & 15;      // k-quad: k = kq*4 + c
    const int T   = (u >> 10) % NTILES;
    const int arr = u / (NTILES * 1024);
    if (arr > 1) return;
    const float* P = arr ? yi : yr;
    const int n_g = T * 64 + n_l;
    float v0 = 0.f, v1 = 0.f, v2 = 0.f, v3 = 0.f;
    if (n_g < N_DICT) {
        v0 = P[(kq * 4 + 0) * N_DICT + n_g];
        v1 = P[(kq * 4 + 1) * N_DICT + n_g];
        v2 = P[(kq * 4 + 2) * N_DICT + n_g];
        v3 = P[(kq * 4 + 3) * N_DICT + n_g];
    }
    v4h V;
    V[0] = (_Float16)v0; V[1] = (_Float16)v1;
    V[2] = (_Float16)v2; V[3] = (_Float16)v3;
    const int h    = kq >> 3;
    const int quad = (kq >> 1) & 3;
    const int half = kq & 1;
    const int fr   = (arr * 2 + h) * 4 + quad;
    yp[((size_t)T * 16 + fr) * 128 + n_l * 2 + half] = V;
}

// ---------------------------------------------------------------------------
// Phase A: f16 2-term MFMA GEMM + per-chunk top-2 (u32 packed comparator).
// ROUND 11: 512-thread blocks (8 waves = 4 wb x 2 wn) over 128 voxels share
// ONE 16 KB y-tile -> LDS/block unchanged, waves/CU cap 16 -> 24+. More
// resident waves per SIMD lets one wave's sim-epilogue VALU overlap other
// waves' MFMA (round 10: 2.3 waves/SIMD ran the pipes serially, 47%+47%).
// ---------------------------------------------------------------------------
__global__ __launch_bounds__(512, 6) void gemm_pre(
    const float* __restrict__ ir, const float* __restrict__ ii,
    const v4h* __restrict__ yp,
    unsigned* __restrict__ cand, int tpc, int slots)
{
    __shared__ float4 ys4[2][1024];         // 2 x 16 KB ping-pong
    __shared__ unsigned xm[4][2][16][2];    // [wb][bt][col][a1,a2]

    const int tid  = threadIdx.x;
    const int wave = tid >> 6, lane = tid & 63;
    const int quad = lane >> 4, col = lane & 15;
    const int wb   = wave >> 1, wn = wave & 1;
    const int vox_w = blockIdx.x * 128 + wb * 32;
    const int chunk = blockIdx.y;
    const int T0 = chunk * tpc;
    const int T1 = (T0 + tpc < NTILES) ? T0 + tpc : NTILES;

    // ---- prologue: DMA tile T0 into buffer 0 (8 waves x 2 x 64 lanes x 16 B) ----
    {
        const float4* src = (const float4*)((const char*)yp + (size_t)T0 * 16384);
#pragma unroll
        for (int p = 0; p < 2; ++p) {
            const int base = wave * 128 + p * 64;            // wave-uniform
            __builtin_amdgcn_global_load_lds(
                (glb_u32*)(src + base + lane),
                (lds_u32*)(&ys4[0][base]), 16, 0, 0);
        }
    }

    // ---- persistent input B-frags: [arr][bt][h] f16 hi/lo (exact split) ----
    v8h fh[2][2][2], fl[2][2][2];
#pragma unroll
    for (int arr = 0; arr < 2; ++arr) {
        const float* P = arr ? ii : ir;
#pragma unroll
        for (int bt = 0; bt < 2; ++bt) {
            const int b = vox_w + bt * 16 + col;
#pragma unroll
            for (int h = 0; h < 2; ++h) {
                v8h H, L;
#pragma unroll
                for (int j = 0; j < 8; ++j) {
                    const int k = h * 32 + quad * 8 + j;
                    float x = P[k * B_VOX + b];
                    _Float16 hh = (_Float16)x;
                    H[j] = hh;
                    L[j] = (_Float16)(x - (float)hh);
                }
                fh[arr][bt][h] = H; fl[arr][bt][h] = L;
            }
        }
    }

    const v4f zc = {0.f, 0.f, 0.f, 0.f};
    unsigned t2a[2] = {0u, 0u}, t2b[2] = {0u, 0u};

    for (int T = T0; T < T1; ++T) {
        const int par = (T - T0) & 1;
        __syncthreads();   // drains DMA(T) into buf[par]; buf[par^1] now free
        if (T + 1 < T1) {  // overlap: DMA(T+1) into the freed buffer
            const float4* src = (const float4*)((const char*)yp + (size_t)(T + 1) * 16384);
#pragma unroll
            for (int p = 0; p < 2; ++p) {
                const int base = wave * 128 + p * 64;
                __builtin_amdgcn_global_load_lds(
                    (glb_u32*)(src + base + lane),
                    (lds_u32*)(&ys4[par ^ 1][base]), 16, 0, 0);
            }
        }
        const v8h* yv = (const v8h*)ys4[par];

        v4f acc[2][2][4];                       // [bt][nt][rr,ri,s1,s2]
#pragma unroll
        for (int h = 0; h < 2; ++h) {
#pragma unroll
            for (int nt = 0; nt < 2; ++nt) {
                const int nrow = (wn * 2 + nt) * 16 + col;
                const v8h yfr = yv[((0 * 2 + h) * 4 + quad) * 64 + nrow];  // yr frag
                const v8h yfi = yv[((1 * 2 + h) * 4 + quad) * 64 + nrow];  // yi frag
#pragma unroll
                for (int bt = 0; bt < 2; ++bt) {
#define MF(A, B, C) __builtin_amdgcn_mfma_f32_16x16x32_f16(A, B, C, 0, 0, 0)
                    if (h == 0) {               // first k-half: C = zero (no init movs)
                        acc[bt][nt][0] = MF(yfr, fh[0][bt][0], zc);
                        acc[bt][nt][1] = MF(yfi, fh[0][bt][0], zc);
                        acc[bt][nt][2] = MF(yfr, fh[1][bt][0], zc);
                        acc[bt][nt][3] = MF(yfi, fh[1][bt][0], zc);
                        acc[bt][nt][0] = MF(yfr, fl[0][bt][0], acc[bt][nt][0]);
                        acc[bt][nt][1] = MF(yfi, fl[0][bt][0], acc[bt][nt][1]);
                        acc[bt][nt][2] = MF(yfr, fl[1][bt][0], acc[bt][nt][2]);
                        acc[bt][nt][3] = MF(yfi, fl[1][bt][0], acc[bt][nt][3]);
                    } else {
                        acc[bt][nt][0] = MF(yfr, fh[0][bt][1], acc[bt][nt][0]);
                        acc[bt][nt][1] = MF(yfi, fh[0][bt][1], acc[bt][nt][1]);
                        acc[bt][nt][2] = MF(yfr, fh[1][bt][1], acc[bt][nt][2]);
                        acc[bt][nt][3] = MF(yfi, fh[1][bt][1], acc[bt][nt][3]);
                        acc[bt][nt][0] = MF(yfr, fl[0][bt][1], acc[bt][nt][0]);
                        acc[bt][nt][1] = MF(yfi, fl[0][bt][1], acc[bt][nt][1]);
                        acc[bt][nt][2] = MF(yfr, fl[1][bt][1], acc[bt][nt][2]);
                        acc[bt][nt][3] = MF(yfi, fl[1][bt][1], acc[bt][nt][3]);
                    }
#undef MF
                }
            }
        }

        // ---- sim + top-2, u32 min/max network ----
        const int tl = T - T0;
#pragma unroll
        for (int nt = 0; nt < 2; ++nt) {
            const int inv_base = 0x1FFF - (tl * 64 + (wn * 2 + nt) * 16 + quad * 4);
#pragma unroll
            for (int bt = 0; bt < 2; ++bt) {
                v4f RR = acc[bt][nt][0], RI = acc[bt][nt][1];
                v4f S1 = acc[bt][nt][2], S2 = acc[bt][nt][3];
#pragma unroll
                for (int r = 0; r < 4; ++r) {
                    float s = fmaf(RR[r], RR[r], fmaf(RI[r], RI[r],
                              fmaf(S1[r], S1[r], S2[r] * S2[r])));
                    unsigned pb = (__float_as_uint(s) & 0xFFFFE000u)
                                | (unsigned)(inv_base - r);
                    unsigned lo = umin32(pb, t2a[bt]);
                    t2a[bt] = umax32(pb, t2a[bt]);
                    t2b[bt] = umax32(t2b[bt], lo);
                }
            }
        }
    }

    // ---- cross-lane top-2 merge over quads (lanes c, c+16, c+32, c+48) ----
    unsigned fa1[2], fa2[2];
#pragma unroll
    for (int bt = 0; bt < 2; ++bt) {
        unsigned a1 = t2a[bt], a2 = t2b[bt];
#pragma unroll
        for (int d = 16; d <= 32; d <<= 1) {
            unsigned b1 = (unsigned)__shfl_xor((int)a1, d, 64);
            unsigned b2 = (unsigned)__shfl_xor((int)a2, d, 64);
            unsigned mn = umin32(a1, b1);
            a1 = umax32(a1, b1);
            a2 = umax32(mn, umax32(a2, b2));
        }
        fa1[bt] = a1; fa2[bt] = a2;
    }
    // ---- cross-wave (wn) merge: wn==1 publishes, wn==0 writes ----
    __syncthreads();
    if (wn == 1 && lane < 16) {
#pragma unroll
        for (int bt = 0; bt < 2; ++bt) { xm[wb][bt][lane][0] = fa1[bt]; xm[wb][bt][lane][1] = fa2[bt]; }
    }
    __syncthreads();
    if (wn == 0 && lane < 16) {
#pragma unroll
        for (int bt = 0; bt < 2; ++bt) {
            unsigned b1 = xm[wb][bt][lane][0];
            unsigned b2 = xm[wb][bt][lane][1];
            unsigned m1 = umax32(fa1[bt], b1);
            unsigned m2 = umax32(umin32(fa1[bt], b1), umax32(fa2[bt], b2));
            const size_t vox = vox_w + bt * 16 + lane;
            cand[vox * slots + chunk * 2 + 0] = m1;
            cand[vox * slots + chunk * 2 + 1] = m2;
        }
    }
}

// ---------------------------------------------------------------------------
// Phase B (fused): exact fp32 rescore of candidates within 2% of approx max,
// winner lane computes scales and writes the 4 output rows directly.
// One wave per voxel.
// ---------------------------------------------------------------------------
__global__ __launch_bounds__(256) void rescore_finish(
    const float* __restrict__ ir, const float* __restrict__ ii,
    const float* __restrict__ yr, const float* __restrict__ yi,
    const float* __restrict__ inv, const float* __restrict__ x1,
    const float* __restrict__ x2,
    const unsigned* __restrict__ cand, int slots, int tpc,
    float* __restrict__ out)
{
    const int tid  = threadIdx.x;
    const int vox  = blockIdx.x * 4 + (tid >> 6);
    const int slot = tid & 63;

    unsigned p = (slot < slots) ? cand[(size_t)vox * slots + slot] : 0u;
    float sa = __uint_as_float(p & 0xFFFFE000u);
    const int chunkc = slot >> 1;
    const int nn = chunkc * tpc * 64 + (0x1FFF - (int)(p & 0x1FFFu));

    float amax = sa;
#pragma unroll
    for (int d = 1; d <= 32; d <<= 1) amax = fmaxf(amax, __shfl_xor(amax, d, 64));

    unsigned long long q = 0ull;
    float rr = 0.f, ri = 0.f, s1 = 0.f, s2 = 0.f;
    const bool active = (slot < slots) && (nn >= 0) && (nn < N_DICT)
                     && (sa >= 0.98f * amax);
    if (active) {
        for (int m = 0; m < M_TIME; ++m) {
            float a  = yr[(size_t)m * N_DICT + nn];
            float c  = yi[(size_t)m * N_DICT + nn];
            float vr = ir[m * B_VOX + vox];
            float vi = ii[m * B_VOX + vox];
            rr = fmaf(vr, a, rr); ri = fmaf(vr, c, ri);
            s1 = fmaf(vi, a, s1); s2 = fmaf(vi, c, s2);
        }
        float s = fmaf(rr, rr, fmaf(ri, ri, fmaf(s1, s1, s2 * s2)));
        q = (((unsigned long long)__float_as_uint(s)) << 32)
          | (unsigned long long)(0xFFFFFFFFu - (unsigned)nn);  // ties -> smaller n
    }
    unsigned long long qm = q;
#pragma unroll
    for (int d = 1; d <= 32; d <<= 1) qm = u64max(qm, __shfl_xor(qm, d, 64));

    if (active && q == qm && qm != 0ull) {       // exactly one lane (n in key)
        float ss = inv[nn];
        out[0 * B_VOX + vox] = (rr + s2) * ss;   // sum(yr*ir + yi*ii) * inv
        out[1 * B_VOX + vox] = (s1 - ri) * ss;   // sum(yr*ii - yi*ir) * inv
        out[2 * B_VOX + vox] = x1[nn];
        out[3 * B_VOX + vox] = x2[nn];
    }
}

// ---------------------------------------------------------------------------
// Last-resort fallbacks (tiny ws): fp32 brute-force argmax + finish.
// ---------------------------------------------------------------------------
__global__ __launch_bounds__(256, 3) void argmax_naive(
    const float* __restrict__ ir, const float* __restrict__ ii,
    const float* __restrict__ yr, const float* __restrict__ yi,
    int* __restrict__ idxout)
{
    int b = blockIdx.x * 256 + threadIdx.x;
    float bs = -1.0f; int bn = 0;
    for (int n = 0; n < N_DICT; ++n) {
        float a_rr = 0.f, a_ri = 0.f, a_s1 = 0.f, a_s2 = 0.f;
        for (int m = 0; m < M_TIME; ++m) {
            float a = yr[m * N_DICT + n], c = yi[m * N_DICT + n];
            float vr = ir[m * B_VOX + b], vi = ii[m * B_VOX + b];
            a_rr = fmaf(vr, a, a_rr); a_ri = fmaf(vr, c, a_ri);
            a_s1 = fmaf(vi, a, a_s1); a_s2 = fmaf(vi, c, a_s2);
        }
        float sim = fmaf(a_rr, a_rr, fmaf(a_ri, a_ri, fmaf(a_s1, a_s1, a_s2 * a_s2)));
        if (sim > bs) { bs = sim; bn = n; }
    }
    idxout[b] = bn;
}

__global__ void finish_k(const float* __restrict__ ir, const float* __restrict__ ii,
                         const float* __restrict__ yr, const float* __restrict__ yi,
                         const float* __restrict__ inv, const float* __restrict__ x1,
                         const float* __restrict__ x2,
                         const int* __restrict__ idxin, float* __restrict__ out)
{
    int b = blockIdx.x * blockDim.x + threadIdx.x;
    int idx = idxin[b];
    float ar = 0.f, ai = 0.f;
    for (int m = 0; m < M_TIME; ++m) {
        float a  = yr[(size_t)m * N_DICT + idx];
        float c  = yi[(size_t)m * N_DICT + idx];
        float vr = ir[m * B_VOX + b];
        float vi = ii[m * B_VOX + b];
        ar = fmaf(a, vr, ar); ar = fmaf(c, vi, ar);
        ai = fmaf(a, vi, ai); ai = fmaf(-c, vr, ai);
    }
    float s = inv[idx];
    out[0 * B_VOX + b] = ar * s;
    out[1 * B_VOX + b] = ai * s;
    out[2 * B_VOX + b] = x1[idx];
    out[3 * B_VOX + b] = x2[idx];
}

extern "C" void kernel_launch(void* const* d_in, const int* in_sizes, int n_in,
                              void* d_out, int out_size, void* d_ws, size_t ws_size,
                              hipStream_t stream) {
    const float* ir  = (const float*)d_in[0];
    const float* ii  = (const float*)d_in[1];
    const float* yr  = (const float*)d_in[2];
    const float* yi  = (const float*)d_in[3];
    const float* inv = (const float*)d_in[4];
    const float* x1  = (const float*)d_in[5];
    const float* x2  = (const float*)d_in[6];
    float* out = (float*)d_out;

    const size_t yp_bytes = (size_t)NTILES * 16384;    // 5.13 MB (f16 frag tiles)

    // pick largest chunk count whose cand buffer fits alongside yp
    int CH = 0;
    for (int c = 32; c >= 4; c >>= 1) {
        size_t cand_bytes = (size_t)B_VOX * (2 * c) * sizeof(unsigned);
        if (ws_size >= cand_bytes + yp_bytes) { CH = c; break; }
    }

    if (CH > 0) {
        const int slots = 2 * CH;
        const int tpc   = (NTILES + CH - 1) / CH;
        unsigned* cand = (unsigned*)d_ws;
        v4h* yp = (v4h*)((char*)d_ws + (size_t)B_VOX * slots * sizeof(unsigned));

        const int units = 2 * NTILES * 1024;
        split_y<<<(units + 255) / 256, 256, 0, stream>>>(yr, yi, yp);
        gemm_pre<<<dim3(B_VOX / 128, CH), 512, 0, stream>>>(ir, ii, yp, cand, tpc, slots);
        rescore_finish<<<B_VOX / 4, 256, 0, stream>>>(ir, ii, yr, yi, inv, x1, x2,
                                                      cand, slots, tpc, out);
    } else {
        int* idxo = (int*)(out + 3 * B_VOX);   // alias out row 3 (read-before-write)
        argmax_naive<<<B_VOX / 256, 256, 0, stream>>>(ir, ii, yr, yi, idxo);
        finish_k<<<B_VOX / 256, 256, 0, stream>>>(ir, ii, yr, yi,
                                                  inv, x1, x2, idxo, out);
    }
}

// Round 12
// 490.196 us; speedup vs baseline: 2.5572x; 2.5572x over previous
//
#include <hip/hip_runtime.h>
#include <hip/hip_bf16.h>
#include <stdint.h>

#define M_TIME 64
#define N_DICT 20000
#define B_VOX  8192

#define NTILES 313    // ceil(20000/64); last tile padded with zeros

typedef _Float16 v8h __attribute__((ext_vector_type(8)));   // 8 f16 (4 VGPRs)
typedef _Float16 v4h __attribute__((ext_vector_type(4)));   // 8 B store unit
typedef float    v4f __attribute__((ext_vector_type(4)));
typedef __attribute__((address_space(3))) unsigned int  lds_u32;
typedef const __attribute__((address_space(1))) unsigned int glb_u32;

__device__ __forceinline__ unsigned long long u64max(unsigned long long a, unsigned long long b) { return a > b ? a : b; }
__device__ __forceinline__ unsigned umin32(unsigned a, unsigned b) { return a < b ? a : b; }
__device__ __forceinline__ unsigned umax32(unsigned a, unsigned b) { return a > b ? a : b; }

// ---------------------------------------------------------------------------
// Prepass: convert y to f16 ONCE, packed in A-fragment order.
// Tile T = 16 fragment-rows fr = (arr*2 + h)*4 + quad; row = 64 n x 8 f16
// (k = h*32 + quad*8 + j). 16 KB/tile. f16 y + exact hi/lo input split gives
// sim rel-err ~6e-4, 30x inside the 2% exact-rescue margin.
// ---------------------------------------------------------------------------
__global__ __launch_bounds__(256) void split_y(
    const float* __restrict__ yr, const float* __restrict__ yi,
    v4h* __restrict__ yp)
{
    const int u = blockIdx.x * 256 + threadIdx.x;   // [arr][T][kq][n_l]
    const int n_l = u & 63;
    const int kq  = (u >> 6) & 15;      // k-quad: k = kq*4 + c
    const int T   = (u >> 10) % NTILES;
    const int arr = u / (NTILES * 1024);
    if (arr > 1) return;
    const float* P = arr ? yi : yr;
    const int n_g = T * 64 + n_l;
    float v0 = 0.f, v1 = 0.f, v2 = 0.f, v3 = 0.f;
    if (n_g < N_DICT) {
        v0 = P[(kq * 4 + 0) * N_DICT + n_g];
        v1 = P[(kq * 4 + 1) * N_DICT + n_g];
        v2 = P[(kq * 4 + 2) * N_DICT + n_g];
        v3 = P[(kq * 4 + 3) * N_DICT + n_g];
    }
    v4h V;
    V[0] = (_Float16)v0; V[1] = (_Float16)v1;
    V[2] = (_Float16)v2; V[3] = (_Float16)v3;
    const int h    = kq >> 3;
    const int quad = (kq >> 1) & 3;
    const int half = kq & 1;
    const int fr   = (arr * 2 + h) * 4 + quad;
    yp[((size_t)T * 16 + fr) * 128 + n_l * 2 + half] = V;
}

// ---------------------------------------------------------------------------
// Phase A: f16 2-term MFMA GEMM + per-chunk top-2 (u32 packed comparator).
// 512-thread blocks (8 waves = 4 wb x 2 wn) over 128 voxels share ONE 16 KB
// y-tile. ROUND 12 FIX: __launch_bounds__(512,4) -> 128-VGPR cap. Round 11's
// (512,6) capped at 85 VGPR and spilled the fragment arrays to scratch
// (VGPR_Count=40, 5.2 GB WRITE traffic, MfmaUtil 6%). The kernel wants ~80
// VGPR -> 6 waves/SIMD; LDS 33.8 KB -> 3 blocks/CU -> 24 waves/CU target.
// ---------------------------------------------------------------------------
__global__ __launch_bounds__(512, 4) void gemm_pre(
    const float* __restrict__ ir, const float* __restrict__ ii,
    const v4h* __restrict__ yp,
    unsigned* __restrict__ cand, int tpc, int slots)
{
    __shared__ float4 ys4[2][1024];         // 2 x 16 KB ping-pong
    __shared__ unsigned xm[4][2][16][2];    // [wb][bt][col][a1,a2]

    const int tid  = threadIdx.x;
    const int wave = tid >> 6, lane = tid & 63;
    const int quad = lane >> 4, col = lane & 15;
    const int wb   = wave >> 1, wn = wave & 1;
    const int vox_w = blockIdx.x * 128 + wb * 32;
    const int chunk = blockIdx.y;
    const int T0 = chunk * tpc;
    const int T1 = (T0 + tpc < NTILES) ? T0 + tpc : NTILES;

    // ---- prologue: DMA tile T0 into buffer 0 (8 waves x 2 x 64 lanes x 16 B) ----
    {
        const float4* src = (const float4*)((const char*)yp + (size_t)T0 * 16384);
#pragma unroll
        for (int p = 0; p < 2; ++p) {
            const int base = wave * 128 + p * 64;            // wave-uniform
            __builtin_amdgcn_global_load_lds(
                (glb_u32*)(src + base + lane),
                (lds_u32*)(&ys4[0][base]), 16, 0, 0);
        }
    }

    // ---- persistent input B-frags: [arr][bt][h] f16 hi/lo (exact split) ----
    v8h fh[2][2][2], fl[2][2][2];
#pragma unroll
    for (int arr = 0; arr < 2; ++arr) {
        const float* P = arr ? ii : ir;
#pragma unroll
        for (int bt = 0; bt < 2; ++bt) {
            const int b = vox_w + bt * 16 + col;
#pragma unroll
            for (int h = 0; h < 2; ++h) {
                v8h H, L;
#pragma unroll
                for (int j = 0; j < 8; ++j) {
                    const int k = h * 32 + quad * 8 + j;
                    float x = P[k * B_VOX + b];
                    _Float16 hh = (_Float16)x;
                    H[j] = hh;
                    L[j] = (_Float16)(x - (float)hh);
                }
                fh[arr][bt][h] = H; fl[arr][bt][h] = L;
            }
        }
    }

    const v4f zc = {0.f, 0.f, 0.f, 0.f};
    unsigned t2a[2] = {0u, 0u}, t2b[2] = {0u, 0u};

    for (int T = T0; T < T1; ++T) {
        const int par = (T - T0) & 1;
        __syncthreads();   // drains DMA(T) into buf[par]; buf[par^1] now free
        if (T + 1 < T1) {  // overlap: DMA(T+1) into the freed buffer
            const float4* src = (const float4*)((const char*)yp + (size_t)(T + 1) * 16384);
#pragma unroll
            for (int p = 0; p < 2; ++p) {
                const int base = wave * 128 + p * 64;
                __builtin_amdgcn_global_load_lds(
                    (glb_u32*)(src + base + lane),
                    (lds_u32*)(&ys4[par ^ 1][base]), 16, 0, 0);
            }
        }
        const v8h* yv = (const v8h*)ys4[par];

        v4f acc[2][2][4];                       // [bt][nt][rr,ri,s1,s2]
#pragma unroll
        for (int h = 0; h < 2; ++h) {
#pragma unroll
            for (int nt = 0; nt < 2; ++nt) {
                const int nrow = (wn * 2 + nt) * 16 + col;
                const v8h yfr = yv[((0 * 2 + h) * 4 + quad) * 64 + nrow];  // yr frag
                const v8h yfi = yv[((1 * 2 + h) * 4 + quad) * 64 + nrow];  // yi frag
#pragma unroll
                for (int bt = 0; bt < 2; ++bt) {
#define MF(A, B, C) __builtin_amdgcn_mfma_f32_16x16x32_f16(A, B, C, 0, 0, 0)
                    if (h == 0) {               // first k-half: C = zero (no init movs)
                        acc[bt][nt][0] = MF(yfr, fh[0][bt][0], zc);
                        acc[bt][nt][1] = MF(yfi, fh[0][bt][0], zc);
                        acc[bt][nt][2] = MF(yfr, fh[1][bt][0], zc);
                        acc[bt][nt][3] = MF(yfi, fh[1][bt][0], zc);
                        acc[bt][nt][0] = MF(yfr, fl[0][bt][0], acc[bt][nt][0]);
                        acc[bt][nt][1] = MF(yfi, fl[0][bt][0], acc[bt][nt][1]);
                        acc[bt][nt][2] = MF(yfr, fl[1][bt][0], acc[bt][nt][2]);
                        acc[bt][nt][3] = MF(yfi, fl[1][bt][0], acc[bt][nt][3]);
                    } else {
                        acc[bt][nt][0] = MF(yfr, fh[0][bt][1], acc[bt][nt][0]);
                        acc[bt][nt][1] = MF(yfi, fh[0][bt][1], acc[bt][nt][1]);
                        acc[bt][nt][2] = MF(yfr, fh[1][bt][1], acc[bt][nt][2]);
                        acc[bt][nt][3] = MF(yfi, fh[1][bt][1], acc[bt][nt][3]);
                        acc[bt][nt][0] = MF(yfr, fl[0][bt][1], acc[bt][nt][0]);
                        acc[bt][nt][1] = MF(yfi, fl[0][bt][1], acc[bt][nt][1]);
                        acc[bt][nt][2] = MF(yfr, fl[1][bt][1], acc[bt][nt][2]);
                        acc[bt][nt][3] = MF(yfi, fl[1][bt][1], acc[bt][nt][3]);
                    }
#undef MF
                }
            }
        }

        // ---- sim + top-2, u32 min/max network ----
        const int tl = T - T0;
#pragma unroll
        for (int nt = 0; nt < 2; ++nt) {
            const int inv_base = 0x1FFF - (tl * 64 + (wn * 2 + nt) * 16 + quad * 4);
#pragma unroll
            for (int bt = 0; bt < 2; ++bt) {
                v4f RR = acc[bt][nt][0], RI = acc[bt][nt][1];
                v4f S1 = acc[bt][nt][2], S2 = acc[bt][nt][3];
#pragma unroll
                for (int r = 0; r < 4; ++r) {
                    float s = fmaf(RR[r], RR[r], fmaf(RI[r], RI[r],
                              fmaf(S1[r], S1[r], S2[r] * S2[r])));
                    unsigned pb = (__float_as_uint(s) & 0xFFFFE000u)
                                | (unsigned)(inv_base - r);
                    unsigned lo = umin32(pb, t2a[bt]);
                    t2a[bt] = umax32(pb, t2a[bt]);
                    t2b[bt] = umax32(t2b[bt], lo);
                }
            }
        }
    }

    // ---- cross-lane top-2 merge over quads (lanes c, c+16, c+32, c+48) ----
    unsigned fa1[2], fa2[2];
#pragma unroll
    for (int bt = 0; bt < 2; ++bt) {
        unsigned a1 = t2a[bt], a2 = t2b[bt];
#pragma unroll
        for (int d = 16; d <= 32; d <<= 1) {
            unsigned b1 = (unsigned)__shfl_xor((int)a1, d, 64);
            unsigned b2 = (unsigned)__shfl_xor((int)a2, d, 64);
            unsigned mn = umin32(a1, b1);
            a1 = umax32(a1, b1);
            a2 = umax32(mn, umax32(a2, b2));
        }
        fa1[bt] = a1; fa2[bt] = a2;
    }
    // ---- cross-wave (wn) merge: wn==1 publishes, wn==0 writes ----
    __syncthreads();
    if (wn == 1 && lane < 16) {
#pragma unroll
        for (int bt = 0; bt < 2; ++bt) { xm[wb][bt][lane][0] = fa1[bt]; xm[wb][bt][lane][1] = fa2[bt]; }
    }
    __syncthreads();
    if (wn == 0 && lane < 16) {
#pragma unroll
        for (int bt = 0; bt < 2; ++bt) {
            unsigned b1 = xm[wb][bt][lane][0];
            unsigned b2 = xm[wb][bt][lane][1];
            unsigned m1 = umax32(fa1[bt], b1);
            unsigned m2 = umax32(umin32(fa1[bt], b1), umax32(fa2[bt], b2));
            const size_t vox = vox_w + bt * 16 + lane;
            cand[vox * slots + chunk * 2 + 0] = m1;
            cand[vox * slots + chunk * 2 + 1] = m2;
        }
    }
}

// ---------------------------------------------------------------------------
// Phase B (fused): exact fp32 rescore of candidates within 2% of approx max,
// winner lane computes scales and writes the 4 output rows directly.
// One wave per voxel.
// ---------------------------------------------------------------------------
__global__ __launch_bounds__(256) void rescore_finish(
    const float* __restrict__ ir, const float* __restrict__ ii,
    const float* __restrict__ yr, const float* __restrict__ yi,
    const float* __restrict__ inv, const float* __restrict__ x1,
    const float* __restrict__ x2,
    const unsigned* __restrict__ cand, int slots, int tpc,
    float* __restrict__ out)
{
    const int tid  = threadIdx.x;
    const int vox  = blockIdx.x * 4 + (tid >> 6);
    const int slot = tid & 63;

    unsigned p = (slot < slots) ? cand[(size_t)vox * slots + slot] : 0u;
    float sa = __uint_as_float(p & 0xFFFFE000u);
    const int chunkc = slot >> 1;
    const int nn = chunkc * tpc * 64 + (0x1FFF - (int)(p & 0x1FFFu));

    float amax = sa;
#pragma unroll
    for (int d = 1; d <= 32; d <<= 1) amax = fmaxf(amax, __shfl_xor(amax, d, 64));

    unsigned long long q = 0ull;
    float rr = 0.f, ri = 0.f, s1 = 0.f, s2 = 0.f;
    const bool active = (slot < slots) && (nn >= 0) && (nn < N_DICT)
                     && (sa >= 0.98f * amax);
    if (active) {
        for (int m = 0; m < M_TIME; ++m) {
            float a  = yr[(size_t)m * N_DICT + nn];
            float c  = yi[(size_t)m * N_DICT + nn];
            float vr = ir[m * B_VOX + vox];
            float vi = ii[m * B_VOX + vox];
            rr = fmaf(vr, a, rr); ri = fmaf(vr, c, ri);
            s1 = fmaf(vi, a, s1); s2 = fmaf(vi, c, s2);
        }
        float s = fmaf(rr, rr, fmaf(ri, ri, fmaf(s1, s1, s2 * s2)));
        q = (((unsigned long long)__float_as_uint(s)) << 32)
          | (unsigned long long)(0xFFFFFFFFu - (unsigned)nn);  // ties -> smaller n
    }
    unsigned long long qm = q;
#pragma unroll
    for (int d = 1; d <= 32; d <<= 1) qm = u64max(qm, __shfl_xor(qm, d, 64));

    if (active && q == qm && qm != 0ull) {       // exactly one lane (n in key)
        float ss = inv[nn];
        out[0 * B_VOX + vox] = (rr + s2) * ss;   // sum(yr*ir + yi*ii) * inv
        out[1 * B_VOX + vox] = (s1 - ri) * ss;   // sum(yr*ii - yi*ir) * inv
        out[2 * B_VOX + vox] = x1[nn];
        out[3 * B_VOX + vox] = x2[nn];
    }
}

// ---------------------------------------------------------------------------
// Last-resort fallbacks (tiny ws): fp32 brute-force argmax + finish.
// ---------------------------------------------------------------------------
__global__ __launch_bounds__(256, 3) void argmax_naive(
    const float* __restrict__ ir, const float* __restrict__ ii,
    const float* __restrict__ yr, const float* __restrict__ yi,
    int* __restrict__ idxout)
{
    int b = blockIdx.x * 256 + threadIdx.x;
    float bs = -1.0f; int bn = 0;
    for (int n = 0; n < N_DICT; ++n) {
        float a_rr = 0.f, a_ri = 0.f, a_s1 = 0.f, a_s2 = 0.f;
        for (int m = 0; m < M_TIME; ++m) {
            float a = yr[m * N_DICT + n], c = yi[m * N_DICT + n];
            float vr = ir[m * B_VOX + b], vi = ii[m * B_VOX + b];
            a_rr = fmaf(vr, a, a_rr); a_ri = fmaf(vr, c, a_ri);
            a_s1 = fmaf(vi, a, a_s1); a_s2 = fmaf(vi, c, a_s2);
        }
        float sim = fmaf(a_rr, a_rr, fmaf(a_ri, a_ri, fmaf(a_s1, a_s1, a_s2 * a_s2)));
        if (sim > bs) { bs = sim; bn = n; }
    }
    idxout[b] = bn;
}

__global__ void finish_k(const float* __restrict__ ir, const float* __restrict__ ii,
                         const float* __restrict__ yr, const float* __restrict__ yi,
                         const float* __restrict__ inv, const float* __restrict__ x1,
                         const float* __restrict__ x2,
                         const int* __restrict__ idxin, float* __restrict__ out)
{
    int b = blockIdx.x * blockDim.x + threadIdx.x;
    int idx = idxin[b];
    float ar = 0.f, ai = 0.f;
    for (int m = 0; m < M_TIME; ++m) {
        float a  = yr[(size_t)m * N_DICT + idx];
        float c  = yi[(size_t)m * N_DICT + idx];
        float vr = ir[m * B_VOX + b];
        float vi = ii[m * B_VOX + b];
        ar = fmaf(a, vr, ar); ar = fmaf(c, vi, ar);
        ai = fmaf(a, vi, ai); ai = fmaf(-c, vr, ai);
    }
    float s = inv[idx];
    out[0 * B_VOX + b] = ar * s;
    out[1 * B_VOX + b] = ai * s;
    out[2 * B_VOX + b] = x1[idx];
    out[3 * B_VOX + b] = x2[idx];
}

extern "C" void kernel_launch(void* const* d_in, const int* in_sizes, int n_in,
                              void* d_out, int out_size, void* d_ws, size_t ws_size,
                              hipStream_t stream) {
    const float* ir  = (const float*)d_in[0];
    const float* ii  = (const float*)d_in[1];
    const float* yr  = (const float*)d_in[2];
    const float* yi  = (const float*)d_in[3];
    const float* inv = (const float*)d_in[4];
    const float* x1  = (const float*)d_in[5];
    const float* x2  = (const float*)d_in[6];
    float* out = (float*)d_out;

    const size_t yp_bytes = (size_t)NTILES * 16384;    // 5.13 MB (f16 frag tiles)

    // pick largest chunk count whose cand buffer fits alongside yp
    int CH = 0;
    for (int c = 32; c >= 4; c >>= 1) {
        size_t cand_bytes = (size_t)B_VOX * (2 * c) * sizeof(unsigned);
        if (ws_size >= cand_bytes + yp_bytes) { CH = c; break; }
    }

    if (CH > 0) {
        const int slots = 2 * CH;
        const int tpc   = (NTILES + CH - 1) / CH;
        unsigned* cand = (unsigned*)d_ws;
        v4h* yp = (v4h*)((char*)d_ws + (size_t)B_VOX * slots * sizeof(unsigned));

        const int units = 2 * NTILES * 1024;
        split_y<<<(units + 255) / 256, 256, 0, stream>>>(yr, yi, yp);
        gemm_pre<<<dim3(B_VOX / 128, CH), 512, 0, stream>>>(ir, ii, yp, cand, tpc, slots);
        rescore_finish<<<B_VOX / 4, 256, 0, stream>>>(ir, ii, yr, yi, inv, x1, x2,
                                                      cand, slots, tpc, out);
    } else {
        int* idxo = (int*)(out + 3 * B_VOX);   // alias out row 3 (read-before-write)
        argmax_naive<<<B_VOX / 256, 256, 0, stream>>>(ir, ii, yr, yi, idxo);
        finish_k<<<B_VOX / 256, 256, 0, stream>>>(ir, ii, yr, yi,
                                                  inv, x1, x2, idxo, out);
    }
}

// Round 13
// 258.497 us; speedup vs baseline: 4.8492x; 1.8963x over previous
//
#include <hip/hip_runtime.h>
#include <hip/hip_bf16.h>
#include <stdint.h>

#define M_TIME 64
#define N_DICT 20000
#define B_VOX  8192

#define NTILES 313    // ceil(20000/64); last tile padded with zeros

typedef _Float16 v8h __attribute__((ext_vector_type(8)));   // 8 f16 (4 VGPRs)
typedef _Float16 v4h __attribute__((ext_vector_type(4)));   // 8 B store unit
typedef float    v4f __attribute__((ext_vector_type(4)));
typedef __attribute__((address_space(3))) unsigned int  lds_u32;
typedef const __attribute__((address_space(1))) unsigned int glb_u32;

__device__ __forceinline__ unsigned long long u64max(unsigned long long a, unsigned long long b) { return a > b ? a : b; }
__device__ __forceinline__ unsigned umin32(unsigned a, unsigned b) { return a < b ? a : b; }
__device__ __forceinline__ unsigned umax32(unsigned a, unsigned b) { return a > b ? a : b; }

// ---------------------------------------------------------------------------
// Prepass: convert y to f16 ONCE, packed in A-fragment order.
// Tile T = 16 fragment-rows fr = (arr*2 + h)*4 + quad; row = 64 n x 8 f16
// (k = h*32 + quad*8 + j). 16 KB/tile. f16 y + exact hi/lo input split gives
// sim rel-err ~6e-4, 30x inside the 2% exact-rescue margin.
// ---------------------------------------------------------------------------
__global__ __launch_bounds__(256) void split_y(
    const float* __restrict__ yr, const float* __restrict__ yi,
    v4h* __restrict__ yp)
{
    const int u = blockIdx.x * 256 + threadIdx.x;   // [arr][T][kq][n_l]
    const int n_l = u & 63;
    const int kq  = (u >> 6) & 15;      // k-quad: k = kq*4 + c
    const int T   = (u >> 10) % NTILES;
    const int arr = u / (NTILES * 1024);
    if (arr > 1) return;
    const float* P = arr ? yi : yr;
    const int n_g = T * 64 + n_l;
    float v0 = 0.f, v1 = 0.f, v2 = 0.f, v3 = 0.f;
    if (n_g < N_DICT) {
        v0 = P[(kq * 4 + 0) * N_DICT + n_g];
        v1 = P[(kq * 4 + 1) * N_DICT + n_g];
        v2 = P[(kq * 4 + 2) * N_DICT + n_g];
        v3 = P[(kq * 4 + 3) * N_DICT + n_g];
    }
    v4h V;
    V[0] = (_Float16)v0; V[1] = (_Float16)v1;
    V[2] = (_Float16)v2; V[3] = (_Float16)v3;
    const int h    = kq >> 3;
    const int quad = (kq >> 1) & 3;
    const int half = kq & 1;
    const int fr   = (arr * 2 + h) * 4 + quad;
    yp[((size_t)T * 16 + fr) * 128 + n_l * 2 + half] = V;
}

// ---------------------------------------------------------------------------
// Phase A: f16 2-term MFMA GEMM + per-chunk top-2 (u32 packed comparator).
// 512-thread blocks (8 waves = 4 wb x 2 wn) over 128 voxels share ONE 16 KB
// y-tile. ROUND 13: __launch_bounds__ 2nd arg is MIN BLOCKS PER CU on this
// toolchain (R11 (512,6)->40 VGPR, R12 (512,4)->64 VGPR; both fit
// cap = 512/(minBlocks*2) for 8-wave blocks). (512,2) -> 4 waves/SIMD ->
// 128-VGPR cap; kernel wants ~100 -> no spill, 2 blocks/CU = 16 waves/CU.
// ---------------------------------------------------------------------------
__global__ __launch_bounds__(512, 2) void gemm_pre(
    const float* __restrict__ ir, const float* __restrict__ ii,
    const v4h* __restrict__ yp,
    unsigned* __restrict__ cand, int tpc, int slots)
{
    __shared__ float4 ys4[2][1024];         // 2 x 16 KB ping-pong
    __shared__ unsigned xm[4][2][16][2];    // [wb][bt][col][a1,a2]

    const int tid  = threadIdx.x;
    const int wave = tid >> 6, lane = tid & 63;
    const int quad = lane >> 4, col = lane & 15;
    const int wb   = wave >> 1, wn = wave & 1;
    const int vox_w = blockIdx.x * 128 + wb * 32;
    const int chunk = blockIdx.y;
    const int T0 = chunk * tpc;
    const int T1 = (T0 + tpc < NTILES) ? T0 + tpc : NTILES;

    // ---- prologue: DMA tile T0 into buffer 0 (8 waves x 2 x 64 lanes x 16 B) ----
    {
        const float4* src = (const float4*)((const char*)yp + (size_t)T0 * 16384);
#pragma unroll
        for (int p = 0; p < 2; ++p) {
            const int base = wave * 128 + p * 64;            // wave-uniform
            __builtin_amdgcn_global_load_lds(
                (glb_u32*)(src + base + lane),
                (lds_u32*)(&ys4[0][base]), 16, 0, 0);
        }
    }

    // ---- persistent input B-frags: [arr][bt][h] f16 hi/lo (exact split) ----
    v8h fh[2][2][2], fl[2][2][2];
#pragma unroll
    for (int arr = 0; arr < 2; ++arr) {
        const float* P = arr ? ii : ir;
#pragma unroll
        for (int bt = 0; bt < 2; ++bt) {
            const int b = vox_w + bt * 16 + col;
#pragma unroll
            for (int h = 0; h < 2; ++h) {
                v8h H, L;
#pragma unroll
                for (int j = 0; j < 8; ++j) {
                    const int k = h * 32 + quad * 8 + j;
                    float x = P[k * B_VOX + b];
                    _Float16 hh = (_Float16)x;
                    H[j] = hh;
                    L[j] = (_Float16)(x - (float)hh);
                }
                fh[arr][bt][h] = H; fl[arr][bt][h] = L;
            }
        }
    }

    const v4f zc = {0.f, 0.f, 0.f, 0.f};
    unsigned t2a[2] = {0u, 0u}, t2b[2] = {0u, 0u};

    for (int T = T0; T < T1; ++T) {
        const int par = (T - T0) & 1;
        __syncthreads();   // drains DMA(T) into buf[par]; buf[par^1] now free
        if (T + 1 < T1) {  // overlap: DMA(T+1) into the freed buffer
            const float4* src = (const float4*)((const char*)yp + (size_t)(T + 1) * 16384);
#pragma unroll
            for (int p = 0; p < 2; ++p) {
                const int base = wave * 128 + p * 64;
                __builtin_amdgcn_global_load_lds(
                    (glb_u32*)(src + base + lane),
                    (lds_u32*)(&ys4[par ^ 1][base]), 16, 0, 0);
            }
        }
        const v8h* yv = (const v8h*)ys4[par];

        v4f acc[2][2][4];                       // [bt][nt][rr,ri,s1,s2]
#pragma unroll
        for (int h = 0; h < 2; ++h) {
#pragma unroll
            for (int nt = 0; nt < 2; ++nt) {
                const int nrow = (wn * 2 + nt) * 16 + col;
                const v8h yfr = yv[((0 * 2 + h) * 4 + quad) * 64 + nrow];  // yr frag
                const v8h yfi = yv[((1 * 2 + h) * 4 + quad) * 64 + nrow];  // yi frag
#pragma unroll
                for (int bt = 0; bt < 2; ++bt) {
#define MF(A, B, C) __builtin_amdgcn_mfma_f32_16x16x32_f16(A, B, C, 0, 0, 0)
                    if (h == 0) {               // first k-half: C = zero (no init movs)
                        acc[bt][nt][0] = MF(yfr, fh[0][bt][0], zc);
                        acc[bt][nt][1] = MF(yfi, fh[0][bt][0], zc);
                        acc[bt][nt][2] = MF(yfr, fh[1][bt][0], zc);
                        acc[bt][nt][3] = MF(yfi, fh[1][bt][0], zc);
                        acc[bt][nt][0] = MF(yfr, fl[0][bt][0], acc[bt][nt][0]);
                        acc[bt][nt][1] = MF(yfi, fl[0][bt][0], acc[bt][nt][1]);
                        acc[bt][nt][2] = MF(yfr, fl[1][bt][0], acc[bt][nt][2]);
                        acc[bt][nt][3] = MF(yfi, fl[1][bt][0], acc[bt][nt][3]);
                    } else {
                        acc[bt][nt][0] = MF(yfr, fh[0][bt][1], acc[bt][nt][0]);
                        acc[bt][nt][1] = MF(yfi, fh[0][bt][1], acc[bt][nt][1]);
                        acc[bt][nt][2] = MF(yfr, fh[1][bt][1], acc[bt][nt][2]);
                        acc[bt][nt][3] = MF(yfi, fh[1][bt][1], acc[bt][nt][3]);
                        acc[bt][nt][0] = MF(yfr, fl[0][bt][1], acc[bt][nt][0]);
                        acc[bt][nt][1] = MF(yfi, fl[0][bt][1], acc[bt][nt][1]);
                        acc[bt][nt][2] = MF(yfr, fl[1][bt][1], acc[bt][nt][2]);
                        acc[bt][nt][3] = MF(yfi, fl[1][bt][1], acc[bt][nt][3]);
                    }
#undef MF
                }
            }
        }

        // ---- sim + top-2, u32 min/max network ----
        const int tl = T - T0;
#pragma unroll
        for (int nt = 0; nt < 2; ++nt) {
            const int inv_base = 0x1FFF - (tl * 64 + (wn * 2 + nt) * 16 + quad * 4);
#pragma unroll
            for (int bt = 0; bt < 2; ++bt) {
                v4f RR = acc[bt][nt][0], RI = acc[bt][nt][1];
                v4f S1 = acc[bt][nt][2], S2 = acc[bt][nt][3];
#pragma unroll
                for (int r = 0; r < 4; ++r) {
                    float s = fmaf(RR[r], RR[r], fmaf(RI[r], RI[r],
                              fmaf(S1[r], S1[r], S2[r] * S2[r])));
                    unsigned pb = (__float_as_uint(s) & 0xFFFFE000u)
                                | (unsigned)(inv_base - r);
                    unsigned lo = umin32(pb, t2a[bt]);
                    t2a[bt] = umax32(pb, t2a[bt]);
                    t2b[bt] = umax32(t2b[bt], lo);
                }
            }
        }
    }

    // ---- cross-lane top-2 merge over quads (lanes c, c+16, c+32, c+48) ----
    unsigned fa1[2], fa2[2];
#pragma unroll
    for (int bt = 0; bt < 2; ++bt) {
        unsigned a1 = t2a[bt], a2 = t2b[bt];
#pragma unroll
        for (int d = 16; d <= 32; d <<= 1) {
            unsigned b1 = (unsigned)__shfl_xor((int)a1, d, 64);
            unsigned b2 = (unsigned)__shfl_xor((int)a2, d, 64);
            unsigned mn = umin32(a1, b1);
            a1 = umax32(a1, b1);
            a2 = umax32(mn, umax32(a2, b2));
        }
        fa1[bt] = a1; fa2[bt] = a2;
    }
    // ---- cross-wave (wn) merge: wn==1 publishes, wn==0 writes ----
    __syncthreads();
    if (wn == 1 && lane < 16) {
#pragma unroll
        for (int bt = 0; bt < 2; ++bt) { xm[wb][bt][lane][0] = fa1[bt]; xm[wb][bt][lane][1] = fa2[bt]; }
    }
    __syncthreads();
    if (wn == 0 && lane < 16) {
#pragma unroll
        for (int bt = 0; bt < 2; ++bt) {
            unsigned b1 = xm[wb][bt][lane][0];
            unsigned b2 = xm[wb][bt][lane][1];
            unsigned m1 = umax32(fa1[bt], b1);
            unsigned m2 = umax32(umin32(fa1[bt], b1), umax32(fa2[bt], b2));
            const size_t vox = vox_w + bt * 16 + lane;
            cand[vox * slots + chunk * 2 + 0] = m1;
            cand[vox * slots + chunk * 2 + 1] = m2;
        }
    }
}

// ---------------------------------------------------------------------------
// Phase B (fused): exact fp32 rescore of candidates within 2% of approx max,
// winner lane computes scales and writes the 4 output rows directly.
// One wave per voxel.
// ---------------------------------------------------------------------------
__global__ __launch_bounds__(256) void rescore_finish(
    const float* __restrict__ ir, const float* __restrict__ ii,
    const float* __restrict__ yr, const float* __restrict__ yi,
    const float* __restrict__ inv, const float* __restrict__ x1,
    const float* __restrict__ x2,
    const unsigned* __restrict__ cand, int slots, int tpc,
    float* __restrict__ out)
{
    const int tid  = threadIdx.x;
    const int vox  = blockIdx.x * 4 + (tid >> 6);
    const int slot = tid & 63;

    unsigned p = (slot < slots) ? cand[(size_t)vox * slots + slot] : 0u;
    float sa = __uint_as_float(p & 0xFFFFE000u);
    const int chunkc = slot >> 1;
    const int nn = chunkc * tpc * 64 + (0x1FFF - (int)(p & 0x1FFFu));

    float amax = sa;
#pragma unroll
    for (int d = 1; d <= 32; d <<= 1) amax = fmaxf(amax, __shfl_xor(amax, d, 64));

    unsigned long long q = 0ull;
    float rr = 0.f, ri = 0.f, s1 = 0.f, s2 = 0.f;
    const bool active = (slot < slots) && (nn >= 0) && (nn < N_DICT)
                     && (sa >= 0.98f * amax);
    if (active) {
        for (int m = 0; m < M_TIME; ++m) {
            float a  = yr[(size_t)m * N_DICT + nn];
            float c  = yi[(size_t)m * N_DICT + nn];
            float vr = ir[m * B_VOX + vox];
            float vi = ii[m * B_VOX + vox];
            rr = fmaf(vr, a, rr); ri = fmaf(vr, c, ri);
            s1 = fmaf(vi, a, s1); s2 = fmaf(vi, c, s2);
        }
        float s = fmaf(rr, rr, fmaf(ri, ri, fmaf(s1, s1, s2 * s2)));
        q = (((unsigned long long)__float_as_uint(s)) << 32)
          | (unsigned long long)(0xFFFFFFFFu - (unsigned)nn);  // ties -> smaller n
    }
    unsigned long long qm = q;
#pragma unroll
    for (int d = 1; d <= 32; d <<= 1) qm = u64max(qm, __shfl_xor(qm, d, 64));

    if (active && q == qm && qm != 0ull) {       // exactly one lane (n in key)
        float ss = inv[nn];
        out[0 * B_VOX + vox] = (rr + s2) * ss;   // sum(yr*ir + yi*ii) * inv
        out[1 * B_VOX + vox] = (s1 - ri) * ss;   // sum(yr*ii - yi*ir) * inv
        out[2 * B_VOX + vox] = x1[nn];
        out[3 * B_VOX + vox] = x2[nn];
    }
}

// ---------------------------------------------------------------------------
// Last-resort fallbacks (tiny ws): fp32 brute-force argmax + finish.
// ---------------------------------------------------------------------------
__global__ __launch_bounds__(256, 3) void argmax_naive(
    const float* __restrict__ ir, const float* __restrict__ ii,
    const float* __restrict__ yr, const float* __restrict__ yi,
    int* __restrict__ idxout)
{
    int b = blockIdx.x * 256 + threadIdx.x;
    float bs = -1.0f; int bn = 0;
    for (int n = 0; n < N_DICT; ++n) {
        float a_rr = 0.f, a_ri = 0.f, a_s1 = 0.f, a_s2 = 0.f;
        for (int m = 0; m < M_TIME; ++m) {
            float a = yr[m * N_DICT + n], c = yi[m * N_DICT + n];
            float vr = ir[m * B_VOX + b], vi = ii[m * B_VOX + b];
            a_rr = fmaf(vr, a, a_rr); a_ri = fmaf(vr, c, a_ri);
            a_s1 = fmaf(vi, a, a_s1); a_s2 = fmaf(vi, c, a_s2);
        }
        float sim = fmaf(a_rr, a_rr, fmaf(a_ri, a_ri, fmaf(a_s1, a_s1, a_s2 * a_s2)));
        if (sim > bs) { bs = sim; bn = n; }
    }
    idxout[b] = bn;
}

__global__ void finish_k(const float* __restrict__ ir, const float* __restrict__ ii,
                         const float* __restrict__ yr, const float* __restrict__ yi,
                         const float* __restrict__ inv, const float* __restrict__ x1,
                         const float* __restrict__ x2,
                         const int* __restrict__ idxin, float* __restrict__ out)
{
    int b = blockIdx.x * blockDim.x + threadIdx.x;
    int idx = idxin[b];
    float ar = 0.f, ai = 0.f;
    for (int m = 0; m < M_TIME; ++m) {
        float a  = yr[(size_t)m * N_DICT + idx];
        float c  = yi[(size_t)m * N_DICT + idx];
        float vr = ir[m * B_VOX + b];
        float vi = ii[m * B_VOX + b];
        ar = fmaf(a, vr, ar); ar = fmaf(c, vi, ar);
        ai = fmaf(a, vi, ai); ai = fmaf(-c, vr, ai);
    }
    float s = inv[idx];
    out[0 * B_VOX + b] = ar * s;
    out[1 * B_VOX + b] = ai * s;
    out[2 * B_VOX + b] = x1[idx];
    out[3 * B_VOX + b] = x2[idx];
}

extern "C" void kernel_launch(void* const* d_in, const int* in_sizes, int n_in,
                              void* d_out, int out_size, void* d_ws, size_t ws_size,
                              hipStream_t stream) {
    const float* ir  = (const float*)d_in[0];
    const float* ii  = (const float*)d_in[1];
    const float* yr  = (const float*)d_in[2];
    const float* yi  = (const float*)d_in[3];
    const float* inv = (const float*)d_in[4];
    const float* x1  = (const float*)d_in[5];
    const float* x2  = (const float*)d_in[6];
    float* out = (float*)d_out;

    const size_t yp_bytes = (size_t)NTILES * 16384;    // 5.13 MB (f16 frag tiles)

    // pick largest chunk count whose cand buffer fits alongside yp
    int CH = 0;
    for (int c = 32; c >= 4; c >>= 1) {
        size_t cand_bytes = (size_t)B_VOX * (2 * c) * sizeof(unsigned);
        if (ws_size >= cand_bytes + yp_bytes) { CH = c; break; }
    }

    if (CH > 0) {
        const int slots = 2 * CH;
        const int tpc   = (NTILES + CH - 1) / CH;
        unsigned* cand = (unsigned*)d_ws;
        v4h* yp = (v4h*)((char*)d_ws + (size_t)B_VOX * slots * sizeof(unsigned));

        const int units = 2 * NTILES * 1024;
        split_y<<<(units + 255) / 256, 256, 0, stream>>>(yr, yi, yp);
        gemm_pre<<<dim3(B_VOX / 128, CH), 512, 0, stream>>>(ir, ii, yp, cand, tpc, slots);
        rescore_finish<<<B_VOX / 4, 256, 0, stream>>>(ir, ii, yr, yi, inv, x1, x2,
                                                      cand, slots, tpc, out);
    } else {
        int* idxo = (int*)(out + 3 * B_VOX);   // alias out row 3 (read-before-write)
        argmax_naive<<<B_VOX / 256, 256, 0, stream>>>(ir, ii, yr, yi, idxo);
        finish_k<<<B_VOX / 256, 256, 0, stream>>>(ir, ii, yr, yi,
                                                  inv, x1, x2, idxo, out);
    }
}

// Round 14
// 247.635 us; speedup vs baseline: 5.0619x; 1.0439x over previous
//
#include <hip/hip_runtime.h>
#include <hip/hip_bf16.h>
#include <stdint.h>

#define M_TIME 64
#define N_DICT 20000
#define B_VOX  8192

#define NTILES 313    // ceil(20000/64); last tile padded with zeros

typedef _Float16 v8h __attribute__((ext_vector_type(8)));   // 8 f16 (4 VGPRs)
typedef _Float16 v4h __attribute__((ext_vector_type(4)));   // 8 B store unit
typedef float    v4f __attribute__((ext_vector_type(4)));
typedef __attribute__((address_space(3))) unsigned int  lds_u32;
typedef const __attribute__((address_space(1))) unsigned int glb_u32;

__device__ __forceinline__ unsigned long long u64max(unsigned long long a, unsigned long long b) { return a > b ? a : b; }
__device__ __forceinline__ unsigned umin32(unsigned a, unsigned b) { return a < b ? a : b; }
__device__ __forceinline__ unsigned umax32(unsigned a, unsigned b) { return a > b ? a : b; }

// ---------------------------------------------------------------------------
// Prepass: convert y to f16 ONCE, packed in A-fragment order.
// Tile T = 16 fragment-rows fr = (arr*2 + h)*4 + quad; row = 64 n x 8 f16
// (k = h*32 + quad*8 + j). 16 KB/tile. f16 y + exact hi/lo input split gives
// sim rel-err ~6e-4, 30x inside the 2% exact-rescue margin.
// ---------------------------------------------------------------------------
__global__ __launch_bounds__(256) void split_y(
    const float* __restrict__ yr, const float* __restrict__ yi,
    v4h* __restrict__ yp)
{
    const int u = blockIdx.x * 256 + threadIdx.x;   // [arr][T][kq][n_l]
    const int n_l = u & 63;
    const int kq  = (u >> 6) & 15;      // k-quad: k = kq*4 + c
    const int T   = (u >> 10) % NTILES;
    const int arr = u / (NTILES * 1024);
    if (arr > 1) return;
    const float* P = arr ? yi : yr;
    const int n_g = T * 64 + n_l;
    float v0 = 0.f, v1 = 0.f, v2 = 0.f, v3 = 0.f;
    if (n_g < N_DICT) {
        v0 = P[(kq * 4 + 0) * N_DICT + n_g];
        v1 = P[(kq * 4 + 1) * N_DICT + n_g];
        v2 = P[(kq * 4 + 2) * N_DICT + n_g];
        v3 = P[(kq * 4 + 3) * N_DICT + n_g];
    }
    v4h V;
    V[0] = (_Float16)v0; V[1] = (_Float16)v1;
    V[2] = (_Float16)v2; V[3] = (_Float16)v3;
    const int h    = kq >> 3;
    const int quad = (kq >> 1) & 3;
    const int half = kq & 1;
    const int fr   = (arr * 2 + h) * 4 + quad;
    yp[((size_t)T * 16 + fr) * 128 + n_l * 2 + half] = V;
}

// ---------------------------------------------------------------------------
// Phase A: f16 2-term MFMA GEMM + per-chunk top-2 (u32 packed comparator).
// ROUND 14: software-pipelined epilogue. Two accumulator sets (A/B) alternate
// across tiles; tile T's epilogue VALU is issued WHILE tile T+1's MFMAs are
// in flight (independent streams from the same wave feed the matrix pipe and
// VALU pipe together). R8-R13 showed runtime ~= MFMA-burst + VALU-burst in
// strict series inside each wave; this breaks that by construction.
// (256,2): 2 blocks/CU min -> 2 waves/SIMD -> 256-VGPR cap (2 acc sets fit).
// ---------------------------------------------------------------------------
__global__ __launch_bounds__(256, 2) void gemm_pre(
    const float* __restrict__ ir, const float* __restrict__ ii,
    const v4h* __restrict__ yp,
    unsigned* __restrict__ cand, int tpc, int slots)
{
    __shared__ float4 ys4[2][1024];         // 2 x 16 KB ping-pong
    __shared__ unsigned xm[2][2][16][2];    // [wb][bt][col][a1,a2]

    const int tid  = threadIdx.x;
    const int wave = tid >> 6, lane = tid & 63;
    const int quad = lane >> 4, col = lane & 15;
    const int wb   = wave >> 1, wn = wave & 1;
    const int vox_w = blockIdx.x * 64 + wb * 32;
    const int chunk = blockIdx.y;
    const int T0 = chunk * tpc;
    const int T1 = (T0 + tpc < NTILES) ? T0 + tpc : NTILES;

    auto dma_tile = [&](int T, int buf) {
        const float4* src = (const float4*)((const char*)yp + (size_t)T * 16384);
#pragma unroll
        for (int p = 0; p < 4; ++p) {
            const int base = p * 256 + wave * 64;            // wave-uniform
            __builtin_amdgcn_global_load_lds(
                (glb_u32*)(src + base + lane),
                (lds_u32*)(&ys4[buf][base]), 16, 0, 0);
        }
    };

    // ---- prologue: DMA tile T0 into buffer 0 ----
    dma_tile(T0, 0);

    // ---- persistent input B-frags: [arr][bt][h] f16 hi/lo (exact split) ----
    v8h fh[2][2][2], fl[2][2][2];
#pragma unroll
    for (int arr = 0; arr < 2; ++arr) {
        const float* P = arr ? ii : ir;
#pragma unroll
        for (int bt = 0; bt < 2; ++bt) {
            const int b = vox_w + bt * 16 + col;
#pragma unroll
            for (int h = 0; h < 2; ++h) {
                v8h H, L;
#pragma unroll
                for (int j = 0; j < 8; ++j) {
                    const int k = h * 32 + quad * 8 + j;
                    float x = P[k * B_VOX + b];
                    _Float16 hh = (_Float16)x;
                    H[j] = hh;
                    L[j] = (_Float16)(x - (float)hh);
                }
                fh[arr][bt][h] = H; fl[arr][bt][h] = L;
            }
        }
    }

    const v4f zc = {0.f, 0.f, 0.f, 0.f};
    unsigned t2a[2] = {0u, 0u}, t2b[2] = {0u, 0u};

    auto compute_tile = [&](v4f (&A)[2][2][4], const v8h* yv) {
#pragma unroll
        for (int h = 0; h < 2; ++h) {
#pragma unroll
            for (int nt = 0; nt < 2; ++nt) {
                const int nrow = (wn * 2 + nt) * 16 + col;
                const v8h yfr = yv[((0 * 2 + h) * 4 + quad) * 64 + nrow];
                const v8h yfi = yv[((1 * 2 + h) * 4 + quad) * 64 + nrow];
#pragma unroll
                for (int bt = 0; bt < 2; ++bt) {
#define MF(Aop, Bop, Cop) __builtin_amdgcn_mfma_f32_16x16x32_f16(Aop, Bop, Cop, 0, 0, 0)
                    if (h == 0) {               // first k-half: C = zero
                        A[bt][nt][0] = MF(yfr, fh[0][bt][0], zc);
                        A[bt][nt][1] = MF(yfi, fh[0][bt][0], zc);
                        A[bt][nt][2] = MF(yfr, fh[1][bt][0], zc);
                        A[bt][nt][3] = MF(yfi, fh[1][bt][0], zc);
                        A[bt][nt][0] = MF(yfr, fl[0][bt][0], A[bt][nt][0]);
                        A[bt][nt][1] = MF(yfi, fl[0][bt][0], A[bt][nt][1]);
                        A[bt][nt][2] = MF(yfr, fl[1][bt][0], A[bt][nt][2]);
                        A[bt][nt][3] = MF(yfi, fl[1][bt][0], A[bt][nt][3]);
                    } else {
                        A[bt][nt][0] = MF(yfr, fh[0][bt][1], A[bt][nt][0]);
                        A[bt][nt][1] = MF(yfi, fh[0][bt][1], A[bt][nt][1]);
                        A[bt][nt][2] = MF(yfr, fh[1][bt][1], A[bt][nt][2]);
                        A[bt][nt][3] = MF(yfi, fh[1][bt][1], A[bt][nt][3]);
                        A[bt][nt][0] = MF(yfr, fl[0][bt][1], A[bt][nt][0]);
                        A[bt][nt][1] = MF(yfi, fl[0][bt][1], A[bt][nt][1]);
                        A[bt][nt][2] = MF(yfr, fl[1][bt][1], A[bt][nt][2]);
                        A[bt][nt][3] = MF(yfi, fl[1][bt][1], A[bt][nt][3]);
                    }
#undef MF
                }
            }
        }
    };

    auto epilogue = [&](v4f (&A)[2][2][4], int TT) {
        const int tl = TT - T0;
#pragma unroll
        for (int nt = 0; nt < 2; ++nt) {
            const int inv_base = 0x1FFF - (tl * 64 + (wn * 2 + nt) * 16 + quad * 4);
#pragma unroll
            for (int bt = 0; bt < 2; ++bt) {
                v4f RR = A[bt][nt][0], RI = A[bt][nt][1];
                v4f S1 = A[bt][nt][2], S2 = A[bt][nt][3];
#pragma unroll
                for (int r = 0; r < 4; ++r) {
                    float s = fmaf(RR[r], RR[r], fmaf(RI[r], RI[r],
                              fmaf(S1[r], S1[r], S2[r] * S2[r])));
                    unsigned pb = (__float_as_uint(s) & 0xFFFFE000u)
                                | (unsigned)(inv_base - r);
                    unsigned lo = umin32(pb, t2a[bt]);
                    t2a[bt] = umax32(pb, t2a[bt]);
                    t2b[bt] = umax32(t2b[bt], lo);
                }
            }
        }
    };

    v4f accA[2][2][4], accB[2][2][4];

    for (int T = T0; T < T1; T += 2) {
        // ---- tile T (even offset) -> buf 0, accumulate into accA ----
        __syncthreads();                       // drains DMA(T) into buf0
        if (T + 1 < T1) dma_tile(T + 1, 1);
        compute_tile(accA, (const v8h*)ys4[0]);
        if (T > T0) epilogue(accB, T - 1);     // overlaps accA's MFMAs

        // ---- tile T+1 (odd offset) -> buf 1, accumulate into accB ----
        if (T + 1 < T1) {
            __syncthreads();                   // accA reads of buf0 done; drains DMA(T+1)
            if (T + 2 < T1) dma_tile(T + 2, 0);
            compute_tile(accB, (const v8h*)ys4[1]);
            epilogue(accA, T);                 // overlaps accB's MFMAs
        } else {
            epilogue(accA, T);                 // odd-count tail
        }
    }
    if (((T1 - T0) & 1) == 0) epilogue(accB, T1 - 1);   // even-count tail

    // ---- cross-lane top-2 merge over quads (lanes c, c+16, c+32, c+48) ----
    unsigned fa1[2], fa2[2];
#pragma unroll
    for (int bt = 0; bt < 2; ++bt) {
        unsigned a1 = t2a[bt], a2 = t2b[bt];
#pragma unroll
        for (int d = 16; d <= 32; d <<= 1) {
            unsigned b1 = (unsigned)__shfl_xor((int)a1, d, 64);
            unsigned b2 = (unsigned)__shfl_xor((int)a2, d, 64);
            unsigned mn = umin32(a1, b1);
            a1 = umax32(a1, b1);
            a2 = umax32(mn, umax32(a2, b2));
        }
        fa1[bt] = a1; fa2[bt] = a2;
    }
    // ---- cross-wave (wn) merge: wn==1 publishes, wn==0 writes ----
    __syncthreads();
    if (wn == 1 && lane < 16) {
#pragma unroll
        for (int bt = 0; bt < 2; ++bt) { xm[wb][bt][lane][0] = fa1[bt]; xm[wb][bt][lane][1] = fa2[bt]; }
    }
    __syncthreads();
    if (wn == 0 && lane < 16) {
#pragma unroll
        for (int bt = 0; bt < 2; ++bt) {
            unsigned b1 = xm[wb][bt][lane][0];
            unsigned b2 = xm[wb][bt][lane][1];
            unsigned m1 = umax32(fa1[bt], b1);
            unsigned m2 = umax32(umin32(fa1[bt], b1), umax32(fa2[bt], b2));
            const size_t vox = vox_w + bt * 16 + lane;
            cand[vox * slots + chunk * 2 + 0] = m1;
            cand[vox * slots + chunk * 2 + 1] = m2;
        }
    }
}

// ---------------------------------------------------------------------------
// Phase B (fused): exact fp32 rescore of candidates within 2% of approx max,
// winner lane computes scales and writes the 4 output rows directly.
// One wave per voxel.
// ---------------------------------------------------------------------------
__global__ __launch_bounds__(256) void rescore_finish(
    const float* __restrict__ ir, const float* __restrict__ ii,
    const float* __restrict__ yr, const float* __restrict__ yi,
    const float* __restrict__ inv, const float* __restrict__ x1,
    const float* __restrict__ x2,
    const unsigned* __restrict__ cand, int slots, int tpc,
    float* __restrict__ out)
{
    const int tid  = threadIdx.x;
    const int vox  = blockIdx.x * 4 + (tid >> 6);
    const int slot = tid & 63;

    unsigned p = (slot < slots) ? cand[(size_t)vox * slots + slot] : 0u;
    float sa = __uint_as_float(p & 0xFFFFE000u);
    const int chunkc = slot >> 1;
    const int nn = chunkc * tpc * 64 + (0x1FFF - (int)(p & 0x1FFFu));

    float amax = sa;
#pragma unroll
    for (int d = 1; d <= 32; d <<= 1) amax = fmaxf(amax, __shfl_xor(amax, d, 64));

    unsigned long long q = 0ull;
    float rr = 0.f, ri = 0.f, s1 = 0.f, s2 = 0.f;
    const bool active = (slot < slots) && (nn >= 0) && (nn < N_DICT)
                     && (sa >= 0.98f * amax);
    if (active) {
        for (int m = 0; m < M_TIME; ++m) {
            float a  = yr[(size_t)m * N_DICT + nn];
            float c  = yi[(size_t)m * N_DICT + nn];
            float vr = ir[m * B_VOX + vox];
            float vi = ii[m * B_VOX + vox];
            rr = fmaf(vr, a, rr); ri = fmaf(vr, c, ri);
            s1 = fmaf(vi, a, s1); s2 = fmaf(vi, c, s2);
        }
        float s = fmaf(rr, rr, fmaf(ri, ri, fmaf(s1, s1, s2 * s2)));
        q = (((unsigned long long)__float_as_uint(s)) << 32)
          | (unsigned long long)(0xFFFFFFFFu - (unsigned)nn);  // ties -> smaller n
    }
    unsigned long long qm = q;
#pragma unroll
    for (int d = 1; d <= 32; d <<= 1) qm = u64max(qm, __shfl_xor(qm, d, 64));

    if (active && q == qm && qm != 0ull) {       // exactly one lane (n in key)
        float ss = inv[nn];
        out[0 * B_VOX + vox] = (rr + s2) * ss;   // sum(yr*ir + yi*ii) * inv
        out[1 * B_VOX + vox] = (s1 - ri) * ss;   // sum(yr*ii - yi*ir) * inv
        out[2 * B_VOX + vox] = x1[nn];
        out[3 * B_VOX + vox] = x2[nn];
    }
}

// ---------------------------------------------------------------------------
// Last-resort fallbacks (tiny ws): fp32 brute-force argmax + finish.
// ---------------------------------------------------------------------------
__global__ __launch_bounds__(256, 3) void argmax_naive(
    const float* __restrict__ ir, const float* __restrict__ ii,
    const float* __restrict__ yr, const float* __restrict__ yi,
    int* __restrict__ idxout)
{
    int b = blockIdx.x * 256 + threadIdx.x;
    float bs = -1.0f; int bn = 0;
    for (int n = 0; n < N_DICT; ++n) {
        float a_rr = 0.f, a_ri = 0.f, a_s1 = 0.f, a_s2 = 0.f;
        for (int m = 0; m < M_TIME; ++m) {
            float a = yr[m * N_DICT + n], c = yi[m * N_DICT + n];
            float vr = ir[m * B_VOX + b], vi = ii[m * B_VOX + b];
            a_rr = fmaf(vr, a, a_rr); a_ri = fmaf(vr, c, a_ri);
            a_s1 = fmaf(vi, a, a_s1); a_s2 = fmaf(vi, c, a_s2);
        }
        float sim = fmaf(a_rr, a_rr, fmaf(a_ri, a_ri, fmaf(a_s1, a_s1, a_s2 * a_s2)));
        if (sim > bs) { bs = sim; bn = n; }
    }
    idxout[b] = bn;
}

__global__ void finish_k(const float* __restrict__ ir, const float* __restrict__ ii,
                         const float* __restrict__ yr, const float* __restrict__ yi,
                         const float* __restrict__ inv, const float* __restrict__ x1,
                         const float* __restrict__ x2,
                         const int* __restrict__ idxin, float* __restrict__ out)
{
    int b = blockIdx.x * blockDim.x + threadIdx.x;
    int idx = idxin[b];
    float ar = 0.f, ai = 0.f;
    for (int m = 0; m < M_TIME; ++m) {
        float a  = yr[(size_t)m * N_DICT + idx];
        float c  = yi[(size_t)m * N_DICT + idx];
        float vr = ir[m * B_VOX + b];
        float vi = ii[m * B_VOX + b];
        ar = fmaf(a, vr, ar); ar = fmaf(c, vi, ar);
        ai = fmaf(a, vi, ai); ai = fmaf(-c, vr, ai);
    }
    float s = inv[idx];
    out[0 * B_VOX + b] = ar * s;
    out[1 * B_VOX + b] = ai * s;
    out[2 * B_VOX + b] = x1[idx];
    out[3 * B_VOX + b] = x2[idx];
}

extern "C" void kernel_launch(void* const* d_in, const int* in_sizes, int n_in,
                              void* d_out, int out_size, void* d_ws, size_t ws_size,
                              hipStream_t stream) {
    const float* ir  = (const float*)d_in[0];
    const float* ii  = (const float*)d_in[1];
    const float* yr  = (const float*)d_in[2];
    const float* yi  = (const float*)d_in[3];
    const float* inv = (const float*)d_in[4];
    const float* x1  = (const float*)d_in[5];
    const float* x2  = (const float*)d_in[6];
    float* out = (float*)d_out;

    const size_t yp_bytes = (size_t)NTILES * 16384;    // 5.13 MB (f16 frag tiles)

    // pick largest chunk count whose cand buffer fits alongside yp
    int CH = 0;
    for (int c = 16; c >= 4; c >>= 1) {
        size_t cand_bytes = (size_t)B_VOX * (2 * c) * sizeof(unsigned);
        if (ws_size >= cand_bytes + yp_bytes) { CH = c; break; }
    }

    if (CH > 0) {
        const int slots = 2 * CH;
        const int tpc   = (NTILES + CH - 1) / CH;
        unsigned* cand = (unsigned*)d_ws;
        v4h* yp = (v4h*)((char*)d_ws + (size_t)B_VOX * slots * sizeof(unsigned));

        const int units = 2 * NTILES * 1024;
        split_y<<<(units + 255) / 256, 256, 0, stream>>>(yr, yi, yp);
        gemm_pre<<<dim3(B_VOX / 64, CH), 256, 0, stream>>>(ir, ii, yp, cand, tpc, slots);
        rescore_finish<<<B_VOX / 4, 256, 0, stream>>>(ir, ii, yr, yi, inv, x1, x2,
                                                      cand, slots, tpc, out);
    } else {
        int* idxo = (int*)(out + 3 * B_VOX);   // alias out row 3 (read-before-write)
        argmax_naive<<<B_VOX / 256, 256, 0, stream>>>(ir, ii, yr, yi, idxo);
        finish_k<<<B_VOX / 256, 256, 0, stream>>>(ir, ii, yr, yi,
                                                  inv, x1, x2, idxo, out);
    }
}

// Round 15
// 201.789 us; speedup vs baseline: 6.2120x; 1.2272x over previous
//
#include <hip/hip_runtime.h>
#include <hip/hip_bf16.h>
#include <stdint.h>

#define M_TIME 64
#define N_DICT 20000
#define B_VOX  8192

#define NTILES 313    // ceil(20000/64); last tile padded with zeros

typedef _Float16 v8h __attribute__((ext_vector_type(8)));   // 8 f16 (4 VGPRs)
typedef _Float16 v4h __attribute__((ext_vector_type(4)));   // 8 B store unit
typedef float    v4f __attribute__((ext_vector_type(4)));
typedef __attribute__((address_space(3))) unsigned int  lds_u32;
typedef const __attribute__((address_space(1))) unsigned int glb_u32;

__device__ __forceinline__ unsigned long long u64max(unsigned long long a, unsigned long long b) { return a > b ? a : b; }
__device__ __forceinline__ unsigned umin32(unsigned a, unsigned b) { return a < b ? a : b; }
__device__ __forceinline__ unsigned umax32(unsigned a, unsigned b) { return a > b ? a : b; }

// ---------------------------------------------------------------------------
// Prepass: convert y to f16 ONCE, packed in A-fragment order.
// Tile T = 16 fragment-rows fr = (arr*2 + h)*4 + quad; row = 64 n x 8 f16
// (k = h*32 + quad*8 + j). 16 KB/tile.
// ---------------------------------------------------------------------------
__global__ __launch_bounds__(256) void split_y(
    const float* __restrict__ yr, const float* __restrict__ yi,
    v4h* __restrict__ yp)
{
    const int u = blockIdx.x * 256 + threadIdx.x;   // [arr][T][kq][n_l]
    const int n_l = u & 63;
    const int kq  = (u >> 6) & 15;      // k-quad: k = kq*4 + c
    const int T   = (u >> 10) % NTILES;
    const int arr = u / (NTILES * 1024);
    if (arr > 1) return;
    const float* P = arr ? yi : yr;
    const int n_g = T * 64 + n_l;
    float v0 = 0.f, v1 = 0.f, v2 = 0.f, v3 = 0.f;
    if (n_g < N_DICT) {
        v0 = P[(kq * 4 + 0) * N_DICT + n_g];
        v1 = P[(kq * 4 + 1) * N_DICT + n_g];
        v2 = P[(kq * 4 + 2) * N_DICT + n_g];
        v3 = P[(kq * 4 + 3) * N_DICT + n_g];
    }
    v4h V;
    V[0] = (_Float16)v0; V[1] = (_Float16)v1;
    V[2] = (_Float16)v2; V[3] = (_Float16)v3;
    const int h    = kq >> 3;
    const int quad = (kq >> 1) & 3;
    const int half = kq & 1;
    const int fr   = (arr * 2 + h) * 4 + quad;
    yp[((size_t)T * 16 + fr) * 128 + n_l * 2 + half] = V;
}

// ---------------------------------------------------------------------------
// Phase A: f16 1-TERM MFMA GEMM + per-chunk top-2 (u32 packed comparator).
// ROUND 15: both operands single-f16 (input lo-term dropped): 32 MFMA/tile
// (was 64) -> matrix-pipe work 86 -> 43 us. Worst-case sim rel-err ~6e-3,
// covered by top-2 candidates + 3% exact-rescue margin (ratio bound 0.988).
// Single acc set + no fl: ~60 VGPR + 64 AGPR ~ 124 unified -> 16-waves/CU
// tier (2x R14 residency) for cross-wave MFMA/VALU overlap.
// ---------------------------------------------------------------------------
__global__ __launch_bounds__(256, 2) void gemm_pre(
    const float* __restrict__ ir, const float* __restrict__ ii,
    const v4h* __restrict__ yp,
    unsigned* __restrict__ cand, int tpc, int slots)
{
    __shared__ float4 ys4[2][1024];         // 2 x 16 KB ping-pong
    __shared__ unsigned xm[2][2][16][2];    // [wb][bt][col][a1,a2]

    const int tid  = threadIdx.x;
    const int wave = tid >> 6, lane = tid & 63;
    const int quad = lane >> 4, col = lane & 15;
    const int wb   = wave >> 1, wn = wave & 1;
    const int vox_w = blockIdx.x * 64 + wb * 32;
    const int chunk = blockIdx.y;
    const int T0 = chunk * tpc;
    const int T1 = (T0 + tpc < NTILES) ? T0 + tpc : NTILES;

    auto dma_tile = [&](int T, int buf) {
        const float4* src = (const float4*)((const char*)yp + (size_t)T * 16384);
#pragma unroll
        for (int p = 0; p < 4; ++p) {
            const int base = p * 256 + wave * 64;            // wave-uniform
            __builtin_amdgcn_global_load_lds(
                (glb_u32*)(src + base + lane),
                (lds_u32*)(&ys4[buf][base]), 16, 0, 0);
        }
    };

    // ---- prologue: DMA tile T0 into buffer 0 ----
    dma_tile(T0, 0);

    // ---- persistent input B-frags: [arr][bt][h] single f16 (RNE) ----
    v8h fh[2][2][2];
#pragma unroll
    for (int arr = 0; arr < 2; ++arr) {
        const float* P = arr ? ii : ir;
#pragma unroll
        for (int bt = 0; bt < 2; ++bt) {
            const int b = vox_w + bt * 16 + col;
#pragma unroll
            for (int h = 0; h < 2; ++h) {
                v8h H;
#pragma unroll
                for (int j = 0; j < 8; ++j) {
                    const int k = h * 32 + quad * 8 + j;
                    H[j] = (_Float16)P[k * B_VOX + b];
                }
                fh[arr][bt][h] = H;
            }
        }
    }

    const v4f zc = {0.f, 0.f, 0.f, 0.f};
    unsigned t2a[2] = {0u, 0u}, t2b[2] = {0u, 0u};

    for (int T = T0; T < T1; ++T) {
        const int par = (T - T0) & 1;
        __syncthreads();   // drains DMA(T) into buf[par]; buf[par^1] now free
        if (T + 1 < T1) dma_tile(T + 1, par ^ 1);
        const v8h* yv = (const v8h*)ys4[par];

        v4f acc[2][2][4];                       // [bt][nt][rr,ri,s1,s2]
#pragma unroll
        for (int h = 0; h < 2; ++h) {
#pragma unroll
            for (int nt = 0; nt < 2; ++nt) {
                const int nrow = (wn * 2 + nt) * 16 + col;
                const v8h yfr = yv[((0 * 2 + h) * 4 + quad) * 64 + nrow];  // yr frag
                const v8h yfi = yv[((1 * 2 + h) * 4 + quad) * 64 + nrow];  // yi frag
#pragma unroll
                for (int bt = 0; bt < 2; ++bt) {
#define MF(A, B, C) __builtin_amdgcn_mfma_f32_16x16x32_f16(A, B, C, 0, 0, 0)
                    if (h == 0) {               // first k-half: C = zero (no init movs)
                        acc[bt][nt][0] = MF(yfr, fh[0][bt][0], zc);
                        acc[bt][nt][1] = MF(yfi, fh[0][bt][0], zc);
                        acc[bt][nt][2] = MF(yfr, fh[1][bt][0], zc);
                        acc[bt][nt][3] = MF(yfi, fh[1][bt][0], zc);
                    } else {
                        acc[bt][nt][0] = MF(yfr, fh[0][bt][1], acc[bt][nt][0]);
                        acc[bt][nt][1] = MF(yfi, fh[0][bt][1], acc[bt][nt][1]);
                        acc[bt][nt][2] = MF(yfr, fh[1][bt][1], acc[bt][nt][2]);
                        acc[bt][nt][3] = MF(yfi, fh[1][bt][1], acc[bt][nt][3]);
                    }
#undef MF
                }
            }
        }

        // ---- sim + top-2, u32 min/max network ----
        const int tl = T - T0;
#pragma unroll
        for (int nt = 0; nt < 2; ++nt) {
            const int inv_base = 0x1FFF - (tl * 64 + (wn * 2 + nt) * 16 + quad * 4);
#pragma unroll
            for (int bt = 0; bt < 2; ++bt) {
                v4f RR = acc[bt][nt][0], RI = acc[bt][nt][1];
                v4f S1 = acc[bt][nt][2], S2 = acc[bt][nt][3];
#pragma unroll
                for (int r = 0; r < 4; ++r) {
                    float s = fmaf(RR[r], RR[r], fmaf(RI[r], RI[r],
                              fmaf(S1[r], S1[r], S2[r] * S2[r])));
                    unsigned pb = (__float_as_uint(s) & 0xFFFFE000u)
                                | (unsigned)(inv_base - r);
                    unsigned lo = umin32(pb, t2a[bt]);
                    t2a[bt] = umax32(pb, t2a[bt]);
                    t2b[bt] = umax32(t2b[bt], lo);
                }
            }
        }
    }

    // ---- cross-lane top-2 merge over quads (lanes c, c+16, c+32, c+48) ----
    unsigned fa1[2], fa2[2];
#pragma unroll
    for (int bt = 0; bt < 2; ++bt) {
        unsigned a1 = t2a[bt], a2 = t2b[bt];
#pragma unroll
        for (int d = 16; d <= 32; d <<= 1) {
            unsigned b1 = (unsigned)__shfl_xor((int)a1, d, 64);
            unsigned b2 = (unsigned)__shfl_xor((int)a2, d, 64);
            unsigned mn = umin32(a1, b1);
            a1 = umax32(a1, b1);
            a2 = umax32(mn, umax32(a2, b2));
        }
        fa1[bt] = a1; fa2[bt] = a2;
    }
    // ---- cross-wave (wn) merge: wn==1 publishes, wn==0 writes ----
    __syncthreads();
    if (wn == 1 && lane < 16) {
#pragma unroll
        for (int bt = 0; bt < 2; ++bt) { xm[wb][bt][lane][0] = fa1[bt]; xm[wb][bt][lane][1] = fa2[bt]; }
    }
    __syncthreads();
    if (wn == 0 && lane < 16) {
#pragma unroll
        for (int bt = 0; bt < 2; ++bt) {
            unsigned b1 = xm[wb][bt][lane][0];
            unsigned b2 = xm[wb][bt][lane][1];
            unsigned m1 = umax32(fa1[bt], b1);
            unsigned m2 = umax32(umin32(fa1[bt], b1), umax32(fa2[bt], b2));
            const size_t vox = vox_w + bt * 16 + lane;
            cand[vox * slots + chunk * 2 + 0] = m1;
            cand[vox * slots + chunk * 2 + 1] = m2;
        }
    }
}

// ---------------------------------------------------------------------------
// Phase B (fused): exact fp32 rescore of candidates within 3% of approx max,
// winner lane computes scales and writes the 4 output rows directly.
// One wave per voxel.
// ---------------------------------------------------------------------------
__global__ __launch_bounds__(256) void rescore_finish(
    const float* __restrict__ ir, const float* __restrict__ ii,
    const float* __restrict__ yr, const float* __restrict__ yi,
    const float* __restrict__ inv, const float* __restrict__ x1,
    const float* __restrict__ x2,
    const unsigned* __restrict__ cand, int slots, int tpc,
    float* __restrict__ out)
{
    const int tid  = threadIdx.x;
    const int vox  = blockIdx.x * 4 + (tid >> 6);
    const int slot = tid & 63;

    unsigned p = (slot < slots) ? cand[(size_t)vox * slots + slot] : 0u;
    float sa = __uint_as_float(p & 0xFFFFE000u);
    const int chunkc = slot >> 1;
    const int nn = chunkc * tpc * 64 + (0x1FFF - (int)(p & 0x1FFFu));

    float amax = sa;
#pragma unroll
    for (int d = 1; d <= 32; d <<= 1) amax = fmaxf(amax, __shfl_xor(amax, d, 64));

    unsigned long long q = 0ull;
    float rr = 0.f, ri = 0.f, s1 = 0.f, s2 = 0.f;
    const bool active = (slot < slots) && (nn >= 0) && (nn < N_DICT)
                     && (sa >= 0.97f * amax);    // widened for 1-term f16 error
    if (active) {
        for (int m = 0; m < M_TIME; ++m) {
            float a  = yr[(size_t)m * N_DICT + nn];
            float c  = yi[(size_t)m * N_DICT + nn];
            float vr = ir[m * B_VOX + vox];
            float vi = ii[m * B_VOX + vox];
            rr = fmaf(vr, a, rr); ri = fmaf(vr, c, ri);
            s1 = fmaf(vi, a, s1); s2 = fmaf(vi, c, s2);
        }
        float s = fmaf(rr, rr, fmaf(ri, ri, fmaf(s1, s1, s2 * s2)));
        q = (((unsigned long long)__float_as_uint(s)) << 32)
          | (unsigned long long)(0xFFFFFFFFu - (unsigned)nn);  // ties -> smaller n
    }
    unsigned long long qm = q;
#pragma unroll
    for (int d = 1; d <= 32; d <<= 1) qm = u64max(qm, __shfl_xor(qm, d, 64));

    if (active && q == qm && qm != 0ull) {       // exactly one lane (n in key)
        float ss = inv[nn];
        out[0 * B_VOX + vox] = (rr + s2) * ss;   // sum(yr*ir + yi*ii) * inv
        out[1 * B_VOX + vox] = (s1 - ri) * ss;   // sum(yr*ii - yi*ir) * inv
        out[2 * B_VOX + vox] = x1[nn];
        out[3 * B_VOX + vox] = x2[nn];
    }
}

// ---------------------------------------------------------------------------
// Last-resort fallbacks (tiny ws): fp32 brute-force argmax + finish.
// ---------------------------------------------------------------------------
__global__ __launch_bounds__(256, 3) void argmax_naive(
    const float* __restrict__ ir, const float* __restrict__ ii,
    const float* __restrict__ yr, const float* __restrict__ yi,
    int* __restrict__ idxout)
{
    int b = blockIdx.x * 256 + threadIdx.x;
    float bs = -1.0f; int bn = 0;
    for (int n = 0; n < N_DICT; ++n) {
        float a_rr = 0.f, a_ri = 0.f, a_s1 = 0.f, a_s2 = 0.f;
        for (int m = 0; m < M_TIME; ++m) {
            float a = yr[m * N_DICT + n], c = yi[m * N_DICT + n];
            float vr = ir[m * B_VOX + b], vi = ii[m * B_VOX + b];
            a_rr = fmaf(vr, a, a_rr); a_ri = fmaf(vr, c, a_ri);
            a_s1 = fmaf(vi, a, a_s1); a_s2 = fmaf(vi, c, a_s2);
        }
        float sim = fmaf(a_rr, a_rr, fmaf(a_ri, a_ri, fmaf(a_s1, a_s1, a_s2 * a_s2)));
        if (sim > bs) { bs = sim; bn = n; }
    }
    idxout[b] = bn;
}

__global__ void finish_k(const float* __restrict__ ir, const float* __restrict__ ii,
                         const float* __restrict__ yr, const float* __restrict__ yi,
                         const float* __restrict__ inv, const float* __restrict__ x1,
                         const float* __restrict__ x2,
                         const int* __restrict__ idxin, float* __restrict__ out)
{
    int b = blockIdx.x * blockDim.x + threadIdx.x;
    int idx = idxin[b];
    float ar = 0.f, ai = 0.f;
    for (int m = 0; m < M_TIME; ++m) {
        float a  = yr[(size_t)m * N_DICT + idx];
        float c  = yi[(size_t)m * N_DICT + idx];
        float vr = ir[m * B_VOX + b];
        float vi = ii[m * B_VOX + b];
        ar = fmaf(a, vr, ar); ar = fmaf(c, vi, ar);
        ai = fmaf(a, vi, ai); ai = fmaf(-c, vr, ai);
    }
    float s = inv[idx];
    out[0 * B_VOX + b] = ar * s;
    out[1 * B_VOX + b] = ai * s;
    out[2 * B_VOX + b] = x1[idx];
    out[3 * B_VOX + b] = x2[idx];
}

extern "C" void kernel_launch(void* const* d_in, const int* in_sizes, int n_in,
                              void* d_out, int out_size, void* d_ws, size_t ws_size,
                              hipStream_t stream) {
    const float* ir  = (const float*)d_in[0];
    const float* ii  = (const float*)d_in[1];
    const float* yr  = (const float*)d_in[2];
    const float* yi  = (const float*)d_in[3];
    const float* inv = (const float*)d_in[4];
    const float* x1  = (const float*)d_in[5];
    const float* x2  = (const float*)d_in[6];
    float* out = (float*)d_out;

    const size_t yp_bytes = (size_t)NTILES * 16384;    // 5.13 MB (f16 frag tiles)

    // pick largest chunk count whose cand buffer fits alongside yp
    int CH = 0;
    for (int c = 16; c >= 4; c >>= 1) {
        size_t cand_bytes = (size_t)B_VOX * (2 * c) * sizeof(unsigned);
        if (ws_size >= cand_bytes + yp_bytes) { CH = c; break; }
    }

    if (CH > 0) {
        const int slots = 2 * CH;
        const int tpc   = (NTILES + CH - 1) / CH;
        unsigned* cand = (unsigned*)d_ws;
        v4h* yp = (v4h*)((char*)d_ws + (size_t)B_VOX * slots * sizeof(unsigned));

        const int units = 2 * NTILES * 1024;
        split_y<<<(units + 255) / 256, 256, 0, stream>>>(yr, yi, yp);
        gemm_pre<<<dim3(B_VOX / 64, CH), 256, 0, stream>>>(ir, ii, yp, cand, tpc, slots);
        rescore_finish<<<B_VOX / 4, 256, 0, stream>>>(ir, ii, yr, yi, inv, x1, x2,
                                                      cand, slots, tpc, out);
    } else {
        int* idxo = (int*)(out + 3 * B_VOX);   // alias out row 3 (read-before-write)
        argmax_naive<<<B_VOX / 256, 256, 0, stream>>>(ir, ii, yr, yi, idxo);
        finish_k<<<B_VOX / 256, 256, 0, stream>>>(ir, ii, yr, yi,
                                                  inv, x1, x2, idxo, out);
    }
}

// Round 16
// 200.549 us; speedup vs baseline: 6.2504x; 1.0062x over previous
//
#include <hip/hip_runtime.h>
#include <hip/hip_bf16.h>
#include <stdint.h>

#define M_TIME 64
#define N_DICT 20000
#define B_VOX  8192

#define NTILES 313    // ceil(20000/64); last tile padded with zeros

typedef _Float16 v8h __attribute__((ext_vector_type(8)));   // 8 f16 (4 VGPRs)
typedef float    v4f __attribute__((ext_vector_type(4)));
typedef __attribute__((address_space(3))) unsigned int  lds_u32;
typedef const __attribute__((address_space(1))) unsigned int glb_u32;

__device__ __forceinline__ unsigned long long u64max(unsigned long long a, unsigned long long b) { return a > b ? a : b; }
__device__ __forceinline__ unsigned umin32(unsigned a, unsigned b) { return a < b ? a : b; }
__device__ __forceinline__ unsigned umax32(unsigned a, unsigned b) { return a > b ? a : b; }

// ---------------------------------------------------------------------------
// Prepass: convert y to f16 ONCE, packed in A-fragment order.
// Tile T = 16 fragment-rows fr = (arr*2 + h)*4 + quad; row = 64 n x 8 f16
// (k = h*32 + quad*8 + j). 16 KB/tile.
// R16: one thread handles a full fragment row-slot (8 k) -> single 16 B
// coalesced store (was 2 x 8 B interleaved).
// ---------------------------------------------------------------------------
__global__ __launch_bounds__(256) void split_y(
    const float* __restrict__ yr, const float* __restrict__ yi,
    v8h* __restrict__ yp)
{
    const int u = blockIdx.x * 256 + threadIdx.x;   // [arr][T][j(8)][n_l(64)]
    const int n_l = u & 63;
    const int j   = (u >> 6) & 7;       // fragment sub-row: k = j*8 .. j*8+7
    const int T   = (u >> 9) % NTILES;
    const int arr = u / (NTILES * 512);
    if (arr > 1) return;
    const float* P = arr ? yi : yr;
    const int n_g = T * 64 + n_l;
    v8h V;
#pragma unroll
    for (int c = 0; c < 8; ++c) {
        float v = 0.f;
        if (n_g < N_DICT) v = P[(j * 8 + c) * N_DICT + n_g];
        V[c] = (_Float16)v;
    }
    const int fr = (arr * 2 + (j >> 2)) * 4 + (j & 3);   // h = j>>2, quad = j&3
    yp[((size_t)T * 16 + fr) * 64 + n_l] = V;
}

// ---------------------------------------------------------------------------
// Phase A: f16 1-term MFMA GEMM + per-chunk top-2 (u32 packed comparator).
// R16: CH=32 chunks (4096 blocks) for finer dispatch-tail granularity;
// epilogue r-outer so the two t2a[bt] min/max chains interleave.
// Residency cap is registers (~124 unified -> 16 waves/CU tier, m69).
// ---------------------------------------------------------------------------
__global__ __launch_bounds__(256, 2) void gemm_pre(
    const float* __restrict__ ir, const float* __restrict__ ii,
    const v8h* __restrict__ yp,
    unsigned* __restrict__ cand, int tpc, int slots)
{
    __shared__ float4 ys4[2][1024];         // 2 x 16 KB ping-pong
    __shared__ unsigned xm[2][2][16][2];    // [wb][bt][col][a1,a2]

    const int tid  = threadIdx.x;
    const int wave = tid >> 6, lane = tid & 63;
    const int quad = lane >> 4, col = lane & 15;
    const int wb   = wave >> 1, wn = wave & 1;
    const int vox_w = blockIdx.x * 64 + wb * 32;
    const int chunk = blockIdx.y;
    const int T0 = chunk * tpc;
    const int T1 = (T0 + tpc < NTILES) ? T0 + tpc : NTILES;

    auto dma_tile = [&](int T, int buf) {
        const float4* src = (const float4*)((const char*)yp + (size_t)T * 16384);
#pragma unroll
        for (int p = 0; p < 4; ++p) {
            const int base = p * 256 + wave * 64;            // wave-uniform
            __builtin_amdgcn_global_load_lds(
                (glb_u32*)(src + base + lane),
                (lds_u32*)(&ys4[buf][base]), 16, 0, 0);
        }
    };

    // ---- prologue: DMA tile T0 into buffer 0 ----
    dma_tile(T0, 0);

    // ---- persistent input B-frags: [arr][bt][h] single f16 (RNE) ----
    v8h fh[2][2][2];
#pragma unroll
    for (int arr = 0; arr < 2; ++arr) {
        const float* P = arr ? ii : ir;
#pragma unroll
        for (int bt = 0; bt < 2; ++bt) {
            const int b = vox_w + bt * 16 + col;
#pragma unroll
            for (int h = 0; h < 2; ++h) {
                v8h H;
#pragma unroll
                for (int j = 0; j < 8; ++j) {
                    const int k = h * 32 + quad * 8 + j;
                    H[j] = (_Float16)P[k * B_VOX + b];
                }
                fh[arr][bt][h] = H;
            }
        }
    }

    const v4f zc = {0.f, 0.f, 0.f, 0.f};
    unsigned t2a[2] = {0u, 0u}, t2b[2] = {0u, 0u};

    for (int T = T0; T < T1; ++T) {
        const int par = (T - T0) & 1;
        __syncthreads();   // drains DMA(T) into buf[par]; buf[par^1] now free
        if (T + 1 < T1) dma_tile(T + 1, par ^ 1);
        const v8h* yv = (const v8h*)ys4[par];

        v4f acc[2][2][4];                       // [bt][nt][rr,ri,s1,s2]
#pragma unroll
        for (int h = 0; h < 2; ++h) {
#pragma unroll
            for (int nt = 0; nt < 2; ++nt) {
                const int nrow = (wn * 2 + nt) * 16 + col;
                const v8h yfr = yv[((0 * 2 + h) * 4 + quad) * 64 + nrow];  // yr frag
                const v8h yfi = yv[((1 * 2 + h) * 4 + quad) * 64 + nrow];  // yi frag
#pragma unroll
                for (int bt = 0; bt < 2; ++bt) {
#define MF(A, B, C) __builtin_amdgcn_mfma_f32_16x16x32_f16(A, B, C, 0, 0, 0)
                    if (h == 0) {               // first k-half: C = zero (no init movs)
                        acc[bt][nt][0] = MF(yfr, fh[0][bt][0], zc);
                        acc[bt][nt][1] = MF(yfi, fh[0][bt][0], zc);
                        acc[bt][nt][2] = MF(yfr, fh[1][bt][0], zc);
                        acc[bt][nt][3] = MF(yfi, fh[1][bt][0], zc);
                    } else {
                        acc[bt][nt][0] = MF(yfr, fh[0][bt][1], acc[bt][nt][0]);
                        acc[bt][nt][1] = MF(yfi, fh[0][bt][1], acc[bt][nt][1]);
                        acc[bt][nt][2] = MF(yfr, fh[1][bt][1], acc[bt][nt][2]);
                        acc[bt][nt][3] = MF(yfi, fh[1][bt][1], acc[bt][nt][3]);
                    }
#undef MF
                }
            }
        }

        // ---- sim + top-2, u32 min/max network (r-outer: bt chains interleave) ----
        const int tl = T - T0;
#pragma unroll
        for (int r = 0; r < 4; ++r) {
#pragma unroll
            for (int nt = 0; nt < 2; ++nt) {
                const int inv_idx = 0x1FFF - (tl * 64 + (wn * 2 + nt) * 16 + quad * 4 + r);
#pragma unroll
                for (int bt = 0; bt < 2; ++bt) {
                    float s = fmaf(acc[bt][nt][0][r], acc[bt][nt][0][r],
                              fmaf(acc[bt][nt][1][r], acc[bt][nt][1][r],
                              fmaf(acc[bt][nt][2][r], acc[bt][nt][2][r],
                                   acc[bt][nt][3][r] * acc[bt][nt][3][r])));
                    unsigned pb = (__float_as_uint(s) & 0xFFFFE000u)
                                | (unsigned)inv_idx;
                    unsigned lo = umin32(pb, t2a[bt]);
                    t2a[bt] = umax32(pb, t2a[bt]);
                    t2b[bt] = umax32(t2b[bt], lo);
                }
            }
        }
    }

    // ---- cross-lane top-2 merge over quads (lanes c, c+16, c+32, c+48) ----
    unsigned fa1[2], fa2[2];
#pragma unroll
    for (int bt = 0; bt < 2; ++bt) {
        unsigned a1 = t2a[bt], a2 = t2b[bt];
#pragma unroll
        for (int d = 16; d <= 32; d <<= 1) {
            unsigned b1 = (unsigned)__shfl_xor((int)a1, d, 64);
            unsigned b2 = (unsigned)__shfl_xor((int)a2, d, 64);
            unsigned mn = umin32(a1, b1);
            a1 = umax32(a1, b1);
            a2 = umax32(mn, umax32(a2, b2));
        }
        fa1[bt] = a1; fa2[bt] = a2;
    }
    // ---- cross-wave (wn) merge: wn==1 publishes, wn==0 writes ----
    __syncthreads();
    if (wn == 1 && lane < 16) {
#pragma unroll
        for (int bt = 0; bt < 2; ++bt) { xm[wb][bt][lane][0] = fa1[bt]; xm[wb][bt][lane][1] = fa2[bt]; }
    }
    __syncthreads();
    if (wn == 0 && lane < 16) {
#pragma unroll
        for (int bt = 0; bt < 2; ++bt) {
            unsigned b1 = xm[wb][bt][lane][0];
            unsigned b2 = xm[wb][bt][lane][1];
            unsigned m1 = umax32(fa1[bt], b1);
            unsigned m2 = umax32(umin32(fa1[bt], b1), umax32(fa2[bt], b2));
            const size_t vox = vox_w + bt * 16 + lane;
            cand[vox * slots + chunk * 2 + 0] = m1;
            cand[vox * slots + chunk * 2 + 1] = m2;
        }
    }
}

// ---------------------------------------------------------------------------
// Phase B (fused): exact fp32 rescore of candidates within 3% of approx max,
// winner lane computes scales and writes the 4 output rows directly.
// One wave per voxel.
// ---------------------------------------------------------------------------
__global__ __launch_bounds__(256) void rescore_finish(
    const float* __restrict__ ir, const float* __restrict__ ii,
    const float* __restrict__ yr, const float* __restrict__ yi,
    const float* __restrict__ inv, const float* __restrict__ x1,
    const float* __restrict__ x2,
    const unsigned* __restrict__ cand, int slots, int tpc,
    float* __restrict__ out)
{
    const int tid  = threadIdx.x;
    const int vox  = blockIdx.x * 4 + (tid >> 6);
    const int slot = tid & 63;

    unsigned p = (slot < slots) ? cand[(size_t)vox * slots + slot] : 0u;
    float sa = __uint_as_float(p & 0xFFFFE000u);
    const int chunkc = slot >> 1;
    const int nn = chunkc * tpc * 64 + (0x1FFF - (int)(p & 0x1FFFu));

    float amax = sa;
#pragma unroll
    for (int d = 1; d <= 32; d <<= 1) amax = fmaxf(amax, __shfl_xor(amax, d, 64));

    unsigned long long q = 0ull;
    float rr = 0.f, ri = 0.f, s1 = 0.f, s2 = 0.f;
    const bool active = (slot < slots) && (nn >= 0) && (nn < N_DICT)
                     && (sa >= 0.97f * amax);    // margin covers 1-term f16 error
    if (active) {
        for (int m = 0; m < M_TIME; ++m) {
            float a  = yr[(size_t)m * N_DICT + nn];
            float c  = yi[(size_t)m * N_DICT + nn];
            float vr = ir[m * B_VOX + vox];
            float vi = ii[m * B_VOX + vox];
            rr = fmaf(vr, a, rr); ri = fmaf(vr, c, ri);
            s1 = fmaf(vi, a, s1); s2 = fmaf(vi, c, s2);
        }
        float s = fmaf(rr, rr, fmaf(ri, ri, fmaf(s1, s1, s2 * s2)));
        q = (((unsigned long long)__float_as_uint(s)) << 32)
          | (unsigned long long)(0xFFFFFFFFu - (unsigned)nn);  // ties -> smaller n
    }
    unsigned long long qm = q;
#pragma unroll
    for (int d = 1; d <= 32; d <<= 1) qm = u64max(qm, __shfl_xor(qm, d, 64));

    if (active && q == qm && qm != 0ull) {       // exactly one lane (n in key)
        float ss = inv[nn];
        out[0 * B_VOX + vox] = (rr + s2) * ss;   // sum(yr*ir + yi*ii) * inv
        out[1 * B_VOX + vox] = (s1 - ri) * ss;   // sum(yr*ii - yi*ir) * inv
        out[2 * B_VOX + vox] = x1[nn];
        out[3 * B_VOX + vox] = x2[nn];
    }
}

// ---------------------------------------------------------------------------
// Last-resort fallbacks (tiny ws): fp32 brute-force argmax + finish.
// ---------------------------------------------------------------------------
__global__ __launch_bounds__(256, 3) void argmax_naive(
    const float* __restrict__ ir, const float* __restrict__ ii,
    const float* __restrict__ yr, const float* __restrict__ yi,
    int* __restrict__ idxout)
{
    int b = blockIdx.x * 256 + threadIdx.x;
    float bs = -1.0f; int bn = 0;
    for (int n = 0; n < N_DICT; ++n) {
        float a_rr = 0.f, a_ri = 0.f, a_s1 = 0.f, a_s2 = 0.f;
        for (int m = 0; m < M_TIME; ++m) {
            float a = yr[m * N_DICT + n], c = yi[m * N_DICT + n];
            float vr = ir[m * B_VOX + b], vi = ii[m * B_VOX + b];
            a_rr = fmaf(vr, a, a_rr); a_ri = fmaf(vr, c, a_ri);
            a_s1 = fmaf(vi, a, a_s1); a_s2 = fmaf(vi, c, a_s2);
        }
        float sim = fmaf(a_rr, a_rr, fmaf(a_ri, a_ri, fmaf(a_s1, a_s1, a_s2 * a_s2)));
        if (sim > bs) { bs = sim; bn = n; }
    }
    idxout[b] = bn;
}

__global__ void finish_k(const float* __restrict__ ir, const float* __restrict__ ii,
                         const float* __restrict__ yr, const float* __restrict__ yi,
                         const float* __restrict__ inv, const float* __restrict__ x1,
                         const float* __restrict__ x2,
                         const int* __restrict__ idxin, float* __restrict__ out)
{
    int b = blockIdx.x * blockDim.x + threadIdx.x;
    int idx = idxin[b];
    float ar = 0.f, ai = 0.f;
    for (int m = 0; m < M_TIME; ++m) {
        float a  = yr[(size_t)m * N_DICT + idx];
        float c  = yi[(size_t)m * N_DICT + idx];
        float vr = ir[m * B_VOX + b];
        float vi = ii[m * B_VOX + b];
        ar = fmaf(a, vr, ar); ar = fmaf(c, vi, ar);
        ai = fmaf(a, vi, ai); ai = fmaf(-c, vr, ai);
    }
    float s = inv[idx];
    out[0 * B_VOX + b] = ar * s;
    out[1 * B_VOX + b] = ai * s;
    out[2 * B_VOX + b] = x1[idx];
    out[3 * B_VOX + b] = x2[idx];
}

extern "C" void kernel_launch(void* const* d_in, const int* in_sizes, int n_in,
                              void* d_out, int out_size, void* d_ws, size_t ws_size,
                              hipStream_t stream) {
    const float* ir  = (const float*)d_in[0];
    const float* ii  = (const float*)d_in[1];
    const float* yr  = (const float*)d_in[2];
    const float* yi  = (const float*)d_in[3];
    const float* inv = (const float*)d_in[4];
    const float* x1  = (const float*)d_in[5];
    const float* x2  = (const float*)d_in[6];
    float* out = (float*)d_out;

    const size_t yp_bytes = (size_t)NTILES * 16384;    // 5.13 MB (f16 frag tiles)

    // pick largest chunk count whose cand buffer fits alongside yp (slots <= 64)
    int CH = 0;
    for (int c = 32; c >= 4; c >>= 1) {
        size_t cand_bytes = (size_t)B_VOX * (2 * c) * sizeof(unsigned);
        if (ws_size >= cand_bytes + yp_bytes) { CH = c; break; }
    }

    if (CH > 0) {
        const int slots = 2 * CH;
        const int tpc   = (NTILES + CH - 1) / CH;
        unsigned* cand = (unsigned*)d_ws;
        v8h* yp = (v8h*)((char*)d_ws + (size_t)B_VOX * slots * sizeof(unsigned));

        const int units = 2 * NTILES * 512;
        split_y<<<(units + 255) / 256, 256, 0, stream>>>(yr, yi, yp);
        gemm_pre<<<dim3(B_VOX / 64, CH), 256, 0, stream>>>(ir, ii, yp, cand, tpc, slots);
        rescore_finish<<<B_VOX / 4, 256, 0, stream>>>(ir, ii, yr, yi, inv, x1, x2,
                                                      cand, slots, tpc, out);
    } else {
        int* idxo = (int*)(out + 3 * B_VOX);   // alias out row 3 (read-before-write)
        argmax_naive<<<B_VOX / 256, 256, 0, stream>>>(ir, ii, yr, yi, idxo);
        finish_k<<<B_VOX / 256, 256, 0, stream>>>(ir, ii, yr, yi,
                                                  inv, x1, x2, idxo, out);
    }
}